// Round 2
// baseline (2128.517 us; speedup 1.0000x reference)
//
#include <hip/hip_runtime.h>
#include <hip/hip_bf16.h>
#include <math.h>

using bf16 = __hip_bfloat16;
typedef __attribute__((ext_vector_type(8))) short s16x8;
typedef __attribute__((ext_vector_type(4))) float f32x4;

__device__ __forceinline__ float bf2f(unsigned short u) {
    return __uint_as_float(((unsigned int)u) << 16);
}
__device__ __forceinline__ unsigned short f2bf(float f) {
    union { bf16 b; unsigned short u; } cv; cv.b = __float2bfloat16(f); return cv.u;
}

// ---------------------------------------------------------------------------
// Depthwise 3x3x3 conv (SAME, zero pad, correlation) + bias + residual. fp32.
// grid = B*D*H*W blocks, block = 384 threads (one per channel)
// ---------------------------------------------------------------------------
__global__ __launch_bounds__(384) void cpe_kernel(
    const float* __restrict__ src, const float* __restrict__ wgt,
    const float* __restrict__ bias, float* __restrict__ out)
{
    const int c = threadIdx.x;
    const int t = blockIdx.x;
    const int b = t >> 13, rem = t & 8191;
    const int d = rem >> 10, hw = rem & 1023, h = hw >> 5, w = hw & 31;
    float acc = bias[c];
    #pragma unroll
    for (int kd = -1; kd <= 1; ++kd) {
        int dd = d + kd; if (dd < 0 || dd >= 8) continue;
        #pragma unroll
        for (int kh = -1; kh <= 1; ++kh) {
            int hh = h + kh; if (hh < 0 || hh >= 32) continue;
            #pragma unroll
            for (int kw = -1; kw <= 1; ++kw) {
                int ww = w + kw; if (ww < 0 || ww >= 32) continue;
                size_t idx = ((((size_t)b * 8 + dd) * 32 + hh) * 32 + ww) * 384 + c;
                float wv = wgt[c * 27 + (kd + 1) * 9 + (kh + 1) * 3 + (kw + 1)];
                acc += src[idx] * wv;
            }
        }
    }
    size_t self = (size_t)t * 384 + c;
    out[self] = src[self] + acc;
}

// ---------------------------------------------------------------------------
// LayerNorm over C=384, fp32 in, bf16 out.  One wave per token, 4 tokens/block.
// ---------------------------------------------------------------------------
__global__ __launch_bounds__(256) void ln_kernel(
    const float* __restrict__ src, const float* __restrict__ gam,
    const float* __restrict__ bet, bf16* __restrict__ out)
{
    const int wid = threadIdx.x >> 6, lane = threadIdx.x & 63;
    const int token = blockIdx.x * 4 + wid;
    const float* p = src + (size_t)token * 384;
    float v[6], s = 0.f, s2 = 0.f;
    #pragma unroll
    for (int i = 0; i < 6; ++i) { v[i] = p[lane + i * 64]; s += v[i]; s2 += v[i] * v[i]; }
    #pragma unroll
    for (int m = 1; m < 64; m <<= 1) { s += __shfl_xor(s, m); s2 += __shfl_xor(s2, m); }
    const float mean = s * (1.f / 384.f);
    const float var  = s2 * (1.f / 384.f) - mean * mean;
    const float rinv = rsqrtf(var + 1e-5f);
    bf16* o = out + (size_t)token * 384;
    #pragma unroll
    for (int i = 0; i < 6; ++i) {
        int cc = lane + i * 64;
        o[cc] = __float2bfloat16((v[i] - mean) * rinv * gam[cc] + bet[cc]);
    }
}

// ---------------------------------------------------------------------------
// GEMM: out[M,N] = A[M,K](bf16, lda=K) @ W[K,N](fp32, ld=ldw) + bias+gelu+res
// block 256 (4 waves), tile 64x64, K-step 32, mfma_f32_16x16x32_bf16.
// flags: 1 = gelu (exact erf), 2 = out fp32 (else bf16).  res fp32 or null.
// grid = (ceil(N/64), M/64)
// ---------------------------------------------------------------------------
__global__ __launch_bounds__(256) void gemm_kernel(
    const bf16* __restrict__ A, const float* __restrict__ W, int ldw,
    void* outp, const float* res, const float* __restrict__ bias,
    int N, int K, int flags)
{
    __shared__ unsigned short As[64 * 40];   // [m][k], stride 40 (80B, 16B-aligned)
    __shared__ unsigned short Bs[64 * 40];   // transposed: [n][k]
    const int tid = threadIdx.x;
    const int m0 = blockIdx.y * 64, n0 = blockIdx.x * 64;
    const int wid = tid >> 6, lane = tid & 63;
    const int moff = (wid >> 1) * 32, noff = (wid & 1) * 32;
    const int lrow = lane & 15, lk = (lane >> 4) * 8;
    const int ar = tid >> 2, ac = (tid & 3) * 8;   // A: 64 rows x 32 cols
    const int br = tid >> 3, bc = (tid & 7) * 8;   // B: 32 rows x 64 cols

    f32x4 acc00 = {0.f,0.f,0.f,0.f}, acc01 = {0.f,0.f,0.f,0.f};
    f32x4 acc10 = {0.f,0.f,0.f,0.f}, acc11 = {0.f,0.f,0.f,0.f};

    for (int k0 = 0; k0 < K; k0 += 32) {
        uint4 av = *(const uint4*)(A + (size_t)(m0 + ar) * K + k0 + ac);
        float4 bv0 = {0.f,0.f,0.f,0.f}, bv1 = {0.f,0.f,0.f,0.f};
        if (n0 + bc < N) {
            const float* wp = W + (size_t)(k0 + br) * ldw + n0 + bc;
            bv0 = *(const float4*)wp;
            bv1 = *(const float4*)(wp + 4);
        }
        *(uint4*)(&As[ar * 40 + ac]) = av;
        unsigned short bs_[8];
        bs_[0] = f2bf(bv0.x); bs_[1] = f2bf(bv0.y); bs_[2] = f2bf(bv0.z); bs_[3] = f2bf(bv0.w);
        bs_[4] = f2bf(bv1.x); bs_[5] = f2bf(bv1.y); bs_[6] = f2bf(bv1.z); bs_[7] = f2bf(bv1.w);
        #pragma unroll
        for (int i = 0; i < 8; ++i) Bs[(bc + i) * 40 + br] = bs_[i];
        __syncthreads();
        s16x8 a0 = *(const s16x8*)(&As[(moff + lrow) * 40 + lk]);
        s16x8 a1 = *(const s16x8*)(&As[(moff + 16 + lrow) * 40 + lk]);
        s16x8 b0 = *(const s16x8*)(&Bs[(noff + lrow) * 40 + lk]);
        s16x8 b1 = *(const s16x8*)(&Bs[(noff + 16 + lrow) * 40 + lk]);
        acc00 = __builtin_amdgcn_mfma_f32_16x16x32_bf16(a0, b0, acc00, 0, 0, 0);
        acc01 = __builtin_amdgcn_mfma_f32_16x16x32_bf16(a0, b1, acc01, 0, 0, 0);
        acc10 = __builtin_amdgcn_mfma_f32_16x16x32_bf16(a1, b0, acc10, 0, 0, 0);
        acc11 = __builtin_amdgcn_mfma_f32_16x16x32_bf16(a1, b1, acc11, 0, 0, 0);
        __syncthreads();
    }

    const bool gelu  = (flags & 1) != 0;
    const bool ofp32 = (flags & 2) != 0;
    f32x4 accs[2][2] = {{acc00, acc01}, {acc10, acc11}};
    #pragma unroll
    for (int mi = 0; mi < 2; ++mi) {
        #pragma unroll
        for (int ni = 0; ni < 2; ++ni) {
            int gn = n0 + noff + ni * 16 + lrow;
            if (gn >= N) continue;
            float bval = bias ? bias[gn] : 0.f;
            #pragma unroll
            for (int r = 0; r < 4; ++r) {
                int gm = m0 + moff + mi * 16 + (lane >> 4) * 4 + r;
                float v = accs[mi][ni][r] + bval;
                if (gelu) v = 0.5f * v * (1.f + erff(v * 0.70710678118f));
                if (res)  v += res[(size_t)gm * N + gn];
                if (ofp32) ((float*)outp)[(size_t)gm * N + gn] = v;
                else       ((bf16*)outp)[(size_t)gm * N + gn] = __float2bfloat16(v);
            }
        }
    }
}

// ---------------------------------------------------------------------------
// Attention part 1: split-K partials of att[c,d] = sum_n scale*K[n,c]*V[n,d]
// kv layout: row (b*8192+n), 768 cols: k at g*192+h*48, v at 384+g*192+h*48
// grid = (32 bgh, 32 splits), block 256; each thread owns 9 (c,d) pairs.
// ---------------------------------------------------------------------------
__global__ __launch_bounds__(256) void attp_kernel(
    const bf16* __restrict__ kvb, float* __restrict__ attp)
{
    const int bgh = blockIdx.x, split = blockIdx.y;
    const int b = bgh >> 3, r = bgh & 7, g = r >> 2, h = r & 3;
    const int kcol = g * 192 + h * 48, vcol = 384 + g * 192 + h * 48;
    const float scale = 0.14433756729740643f;  // 48^-0.5
    __shared__ float Ks[64 * 48];
    __shared__ float Vs[64 * 48];
    const int tid = threadIdx.x;
    int cc[9], dd9[9];
    float acc[9];
    #pragma unroll
    for (int p = 0; p < 9; ++p) {
        int pid = tid + p * 256; cc[p] = pid / 48; dd9[p] = pid % 48; acc[p] = 0.f;
    }
    for (int chunk = 0; chunk < 4; ++chunk) {
        const int nbase = split * 256 + chunk * 64;
        for (int i = tid; i < 64 * 48; i += 256) {
            int row = i / 48, col = i % 48;
            size_t gi = (size_t)(b * 8192 + nbase + row) * 768;
            Ks[i] = scale * (float)kvb[gi + kcol + col];
            Vs[i] = (float)kvb[gi + vcol + col];
        }
        __syncthreads();
        for (int n = 0; n < 64; ++n) {
            const float* kr = &Ks[n * 48];
            const float* vr = &Vs[n * 48];
            #pragma unroll
            for (int p = 0; p < 9; ++p) acc[p] += kr[cc[p]] * vr[dd9[p]];
        }
        __syncthreads();
    }
    float* op = attp + ((size_t)bgh * 32 + split) * 2304;
    #pragma unroll
    for (int p = 0; p < 9; ++p) op[tid + p * 256] = acc[p];
}

// ---------------------------------------------------------------------------
// Attention part 2: reduce 32 splits, fp32 softmax over rows, cast to bf16.
// grid = 32 blocks (bgh), block 256.
// ---------------------------------------------------------------------------
__global__ __launch_bounds__(256) void attred_kernel(
    const float* __restrict__ attp, bf16* __restrict__ att)
{
    const int bgh = blockIdx.x, tid = threadIdx.x;
    __shared__ float s[2304];
    for (int i = tid; i < 2304; i += 256) {
        float a = 0.f;
        for (int sp = 0; sp < 32; ++sp) a += attp[((size_t)bgh * 32 + sp) * 2304 + i];
        s[i] = a;
    }
    __syncthreads();
    if (tid < 48) {
        const int base = tid * 48;
        float mx = -1e30f;
        for (int d = 0; d < 48; ++d) mx = fmaxf(mx, s[base + d]);
        float sum = 0.f;
        for (int d = 0; d < 48; ++d) sum += expf(s[base + d] - mx);
        float inv = 1.f / sum;
        for (int d = 0; d < 48; ++d)
            att[(size_t)bgh * 2304 + base + d] = __float2bfloat16(expf(s[base + d] - mx) * inv);
    }
}

// ---------------------------------------------------------------------------
// y[n,d] = sum_e att[d,e] * q[n, g*48+e], written with the faithful scrambled
// reshape: row' = b*8192 + (2h+g)*1024 + n/8, col' = (n%8)*48 + d.
// grid = 4096 (b * n0), block 384 (one thread per output col').
// ---------------------------------------------------------------------------
__global__ __launch_bounds__(384) void y_kernel(
    const bf16* __restrict__ q, const bf16* __restrict__ att, bf16* __restrict__ y)
{
    const int blk = blockIdx.x;
    const int b = blk >> 10, n0 = blk & 1023;
    const int tid = threadIdx.x;
    __shared__ float qs[8 * 96];
    __shared__ unsigned short as_[8 * 48 * 50];  // [h2g][d][e], stride 50 (pad)
    for (int i = tid; i < 8 * 96; i += 384) {
        int nl = i / 96, col = i % 96;
        qs[i] = (float)q[(size_t)(b * 8192 + n0 * 8 + nl) * 96 + col];
    }
    const unsigned short* attu = (const unsigned short*)att;
    for (int i = tid; i < 8 * 2304; i += 384) {
        int h2g = i / 2304, j = i % 2304, d = j / 48, e = j % 48;
        int g = h2g & 1, hh = h2g >> 1;
        as_[h2g * 2400 + d * 50 + e] = attu[(size_t)(b * 8 + g * 4 + hh) * 2304 + j];
    }
    __syncthreads();
    const int nl = tid / 48, d = tid % 48;
    #pragma unroll
    for (int h2g = 0; h2g < 8; ++h2g) {
        const int g = h2g & 1;
        const float* qp = &qs[nl * 96 + g * 48];
        const unsigned short* ap = &as_[h2g * 2400 + d * 50];
        float acc = 0.f;
        #pragma unroll 8
        for (int e = 0; e < 48; ++e) acc += qp[e] * bf2f(ap[e]);
        y[(size_t)(b * 8192 + h2g * 1024 + n0) * 384 + tid] = __float2bfloat16(acc);
    }
}

// ---------------------------------------------------------------------------
extern "C" void kernel_launch(void* const* d_in, const int* in_sizes, int n_in,
                              void* d_out, int out_size, void* d_ws, size_t ws_size,
                              hipStream_t stream)
{
    (void)in_sizes; (void)n_in; (void)out_size; (void)ws_size;
    const float* x      = (const float*)d_in[0];
    const float* cpe0_w = (const float*)d_in[2];
    const float* cpe0_b = (const float*)d_in[3];
    const float* cpe1_w = (const float*)d_in[4];
    const float* cpe1_b = (const float*)d_in[5];
    const float* n1g    = (const float*)d_in[6];
    const float* n1b    = (const float*)d_in[7];
    const float* q_w    = (const float*)d_in[8];
    const float* kv_w   = (const float*)d_in[9];
    const float* proj_w = (const float*)d_in[10];
    const float* proj_b = (const float*)d_in[11];
    const float* n2g    = (const float*)d_in[12];
    const float* n2b    = (const float*)d_in[13];
    const float* w1     = (const float*)d_in[14];
    const float* b1     = (const float*)d_in[15];
    const float* w2     = (const float*)d_in[16];
    const float* b2     = (const float*)d_in[17];

    char* ws = (char*)d_ws;
    float* xf   = (float*)(ws + 0);           // 50,331,648  residual stream fp32
    bf16*  t    = (bf16*)(ws + 50331648);     // 25,165,824  LN output bf16
    char*  Cr   =         ws + 75497472;      // 50,331,648  kv -> xf2 -> mlp acc
    bf16*  kvb  = (bf16*)Cr;
    float* xf2  = (float*)Cr;
    float* accO = (float*)Cr;
    bf16*  q    = (bf16*)(ws + 125829120);    //  6,291,456
    float* attp = (float*)(ws + 132120576);   //  9,437,184
    bf16*  att  = (bf16*)(ws + 141557760);    //    147,456
    bf16*  yb   = (bf16*)(ws + 141705216);    // 33,554,432  y -> h1 chunk
    bf16*  h1   = yb;

    const int NTOK = 32768;

    // 1. CPE0: xf = x + dwconv(x) + b   (fp32)
    cpe_kernel<<<dim3(NTOK), dim3(384), 0, stream>>>(x, cpe0_w, cpe0_b, xf);
    // 2. LN1: t = LN(xf)
    ln_kernel<<<dim3(NTOK / 4), dim3(256), 0, stream>>>(xf, n1g, n1b, t);
    // 3/4. q and kv projections (bf16 out)
    gemm_kernel<<<dim3(2, 512), dim3(256), 0, stream>>>(t, q_w, 96, q, nullptr, nullptr, 96, 384, 0);
    gemm_kernel<<<dim3(12, 512), dim3(256), 0, stream>>>(t, kv_w, 768, kvb, nullptr, nullptr, 768, 384, 0);
    // 5/6. channel attention scores + softmax
    attp_kernel<<<dim3(32, 32), dim3(256), 0, stream>>>(kvb, attp);
    attred_kernel<<<dim3(32), dim3(256), 0, stream>>>(attp, att);
    // 7. y = q @ att^T with scrambled reshape
    y_kernel<<<dim3(4096), dim3(384), 0, stream>>>(q, att, yb);
    // 8. proj: xf2 = y @ proj_w + proj_b + xf   (fp32)
    gemm_kernel<<<dim3(6, 512), dim3(256), 0, stream>>>(yb, proj_w, 384, xf2, xf, proj_b, 384, 384, 2);
    // 9. CPE1: xf(=xf3) = xf2 + dwconv(xf2) + b
    cpe_kernel<<<dim3(NTOK), dim3(384), 0, stream>>>(xf2, cpe1_w, cpe1_b, xf);
    // 10. LN2: t = LN(xf3)
    ln_kernel<<<dim3(NTOK / 4), dim3(256), 0, stream>>>(xf, n2g, n2b, t);
    // 11. MLP in 3 K-chunks of 512: out = xf3 + b2 + sum_j gelu(t@W1_j+b1_j)@W2_j
    for (int j = 0; j < 3; ++j) {
        gemm_kernel<<<dim3(8, 512), dim3(256), 0, stream>>>(
            t, w1 + j * 512, 1536, h1, nullptr, b1 + j * 512, 512, 384, 1);
        gemm_kernel<<<dim3(6, 512), dim3(256), 0, stream>>>(
            h1, w2 + (size_t)j * 512 * 384, 384,
            (j == 2) ? (void*)d_out : (void*)accO,
            j == 0 ? xf : accO, j == 0 ? b2 : nullptr, 384, 512, 2);
    }
}

// Round 3
// 1164.715 us; speedup vs baseline: 1.8275x; 1.8275x over previous
//
#include <hip/hip_runtime.h>
#include <hip/hip_bf16.h>
#include <math.h>

using bf16 = __hip_bfloat16;
typedef __attribute__((ext_vector_type(8))) short s16x8;
typedef __attribute__((ext_vector_type(4))) float f32x4;

__device__ __forceinline__ float bf2f(unsigned short u) {
    return __uint_as_float(((unsigned int)u) << 16);
}

// ---------------------------------------------------------------------------
// prep: fp32 -> bf16 weight conversion (grid-stride)
// ---------------------------------------------------------------------------
__global__ __launch_bounds__(256) void f2b_kernel(
    const float* __restrict__ a, bf16* __restrict__ o, int n)
{
    for (int i = blockIdx.x * 256 + threadIdx.x; i < n; i += gridDim.x * 256)
        o[i] = __float2bfloat16(a[i]);
}

// prep: conv weight transpose [384][27] -> [27][384]
__global__ __launch_bounds__(256) void wtr_kernel(
    const float* __restrict__ w0, float* __restrict__ t0,
    const float* __restrict__ w1, float* __restrict__ t1)
{
    int i = blockIdx.x * 256 + threadIdx.x;
    if (i < 384 * 27) {
        int c = i / 27, tap = i % 27;
        t0[tap * 384 + c] = w0[i];
        t1[tap * 384 + c] = w1[i];
    }
}

// ---------------------------------------------------------------------------
// Depthwise 3x3x3 conv (SAME, zero pad) + bias + residual. fp32 in/out.
// thread = (voxel, channel-quad). block 384 = 4 voxels x 96 quads.
// grid = 8192. All 27 taps are unconditional clamped float4 loads * mask ->
// independent dwordx4 stream the compiler can software-pipeline.
// wgtT layout: [27][384].
// ---------------------------------------------------------------------------
__global__ __launch_bounds__(384) void cpe_kernel(
    const float* __restrict__ src, const float* __restrict__ wgtT,
    const float* __restrict__ bias, float* __restrict__ out)
{
    const int tid = threadIdx.x;
    const int v4 = tid / 96, q = tid % 96, c = q * 4;
    const int blk = blockIdx.x;
    const int w = ((blk & 7) << 2) + v4;
    const int h = (blk >> 3) & 31;
    const int d = (blk >> 8) & 7;
    const int b = blk >> 11;

    const float4 bv = *(const float4*)(bias + c);
    float ax = bv.x, ay = bv.y, az = bv.z, aw = bv.w;

    #pragma unroll
    for (int kd = 0; kd < 3; ++kd) {
        const int dd = d + kd - 1;
        const float dm = ((unsigned)dd < 8u) ? 1.f : 0.f;
        const int ddc = min(max(dd, 0), 7);
        #pragma unroll
        for (int kh = 0; kh < 3; ++kh) {
            const int hh = h + kh - 1;
            const float hm = dm * (((unsigned)hh < 32u) ? 1.f : 0.f);
            const int hhc = min(max(hh, 0), 31);
            #pragma unroll
            for (int kw = 0; kw < 3; ++kw) {
                const int ww = w + kw - 1;
                const float m = hm * (((unsigned)ww < 32u) ? 1.f : 0.f);
                const int wwc = min(max(ww, 0), 31);
                const size_t si = ((((size_t)b * 8 + ddc) * 32 + hhc) * 32 + wwc) * 384 + c;
                const float4 sv = *(const float4*)(src + si);
                const float4 wv = *(const float4*)(wgtT + (kd * 9 + kh * 3 + kw) * 384 + c);
                ax += m * sv.x * wv.x;
                ay += m * sv.y * wv.y;
                az += m * sv.z * wv.z;
                aw += m * sv.w * wv.w;
            }
        }
    }
    const size_t self = ((((size_t)b * 8 + d) * 32 + h) * 32 + w) * 384 + c;
    const float4 s0 = *(const float4*)(src + self);
    float4 r;
    r.x = s0.x + ax; r.y = s0.y + ay; r.z = s0.z + az; r.w = s0.w + aw;
    *(float4*)(out + self) = r;
}

// ---------------------------------------------------------------------------
// LayerNorm over C=384, fp32 in, bf16 out.  One wave per token, 4 tokens/block.
// ---------------------------------------------------------------------------
__global__ __launch_bounds__(256) void ln_kernel(
    const float* __restrict__ src, const float* __restrict__ gam,
    const float* __restrict__ bet, bf16* __restrict__ out)
{
    const int wid = threadIdx.x >> 6, lane = threadIdx.x & 63;
    const int token = blockIdx.x * 4 + wid;
    const float* p = src + (size_t)token * 384;
    float v[6], s = 0.f, s2 = 0.f;
    #pragma unroll
    for (int i = 0; i < 6; ++i) { v[i] = p[lane + i * 64]; s += v[i]; s2 += v[i] * v[i]; }
    #pragma unroll
    for (int m = 1; m < 64; m <<= 1) { s += __shfl_xor(s, m); s2 += __shfl_xor(s2, m); }
    const float mean = s * (1.f / 384.f);
    const float var  = s2 * (1.f / 384.f) - mean * mean;
    const float rinv = rsqrtf(var + 1e-5f);
    bf16* o = out + (size_t)token * 384;
    #pragma unroll
    for (int i = 0; i < 6; ++i) {
        int cc = lane + i * 64;
        o[cc] = __float2bfloat16((v[i] - mean) * rinv * gam[cc] + bet[cc]);
    }
}

// ---------------------------------------------------------------------------
// GEMM: out[M,N] = A[M,K](bf16, lda=K) @ W[K,N](bf16, ld=ldw) + bias+gelu+res
// block 256 (4 waves), tile 64x64, K-step 32, mfma_f32_16x16x32_bf16.
// flags: 1 = gelu (exact erf), 2 = out fp32 (else bf16).  res fp32 or null.
// grid = (ceil(N/64), M/64)
// ---------------------------------------------------------------------------
__global__ __launch_bounds__(256) void gemm_kernel(
    const bf16* __restrict__ A, const bf16* __restrict__ W, int ldw,
    void* outp, const float* res, const float* __restrict__ bias,
    int N, int K, int flags)
{
    __shared__ unsigned short As[64 * 40];   // [m][k], stride 40 (80B, 16B-aligned)
    __shared__ unsigned short Bs[64 * 40];   // transposed: [n][k]
    const int tid = threadIdx.x;
    const int m0 = blockIdx.y * 64, n0 = blockIdx.x * 64;
    const int wid = tid >> 6, lane = tid & 63;
    const int moff = (wid >> 1) * 32, noff = (wid & 1) * 32;
    const int lrow = lane & 15, lk = (lane >> 4) * 8;
    const int ar = tid >> 2, ac = (tid & 3) * 8;   // A: 64 rows x 32 cols
    const int br = tid >> 3, bc = (tid & 7) * 8;   // B: 32 rows x 64 cols

    f32x4 acc00 = {0.f,0.f,0.f,0.f}, acc01 = {0.f,0.f,0.f,0.f};
    f32x4 acc10 = {0.f,0.f,0.f,0.f}, acc11 = {0.f,0.f,0.f,0.f};

    for (int k0 = 0; k0 < K; k0 += 32) {
        uint4 av = *(const uint4*)(A + (size_t)(m0 + ar) * K + k0 + ac);
        uint4 bv = make_uint4(0u, 0u, 0u, 0u);
        if (n0 + bc < N)
            bv = *(const uint4*)(W + (size_t)(k0 + br) * ldw + n0 + bc);
        *(uint4*)(&As[ar * 40 + ac]) = av;
        const unsigned short* bsp = (const unsigned short*)&bv;
        #pragma unroll
        for (int i = 0; i < 8; ++i) Bs[(bc + i) * 40 + br] = bsp[i];
        __syncthreads();
        s16x8 a0 = *(const s16x8*)(&As[(moff + lrow) * 40 + lk]);
        s16x8 a1 = *(const s16x8*)(&As[(moff + 16 + lrow) * 40 + lk]);
        s16x8 b0 = *(const s16x8*)(&Bs[(noff + lrow) * 40 + lk]);
        s16x8 b1 = *(const s16x8*)(&Bs[(noff + 16 + lrow) * 40 + lk]);
        acc00 = __builtin_amdgcn_mfma_f32_16x16x32_bf16(a0, b0, acc00, 0, 0, 0);
        acc01 = __builtin_amdgcn_mfma_f32_16x16x32_bf16(a0, b1, acc01, 0, 0, 0);
        acc10 = __builtin_amdgcn_mfma_f32_16x16x32_bf16(a1, b0, acc10, 0, 0, 0);
        acc11 = __builtin_amdgcn_mfma_f32_16x16x32_bf16(a1, b1, acc11, 0, 0, 0);
        __syncthreads();
    }

    const bool gelu  = (flags & 1) != 0;
    const bool ofp32 = (flags & 2) != 0;
    f32x4 accs[2][2] = {{acc00, acc01}, {acc10, acc11}};
    #pragma unroll
    for (int mi = 0; mi < 2; ++mi) {
        #pragma unroll
        for (int ni = 0; ni < 2; ++ni) {
            int gn = n0 + noff + ni * 16 + lrow;
            if (gn >= N) continue;
            float bval = bias ? bias[gn] : 0.f;
            #pragma unroll
            for (int r = 0; r < 4; ++r) {
                int gm = m0 + moff + mi * 16 + (lane >> 4) * 4 + r;
                float v = accs[mi][ni][r] + bval;
                if (gelu) v = 0.5f * v * (1.f + erff(v * 0.70710678118f));
                if (res)  v += res[(size_t)gm * N + gn];
                if (ofp32) ((float*)outp)[(size_t)gm * N + gn] = v;
                else       ((bf16*)outp)[(size_t)gm * N + gn] = __float2bfloat16(v);
            }
        }
    }
}

// ---------------------------------------------------------------------------
// Attention part 1: split-K partials of att[c,d] = sum_n scale*K[n,c]*V[n,d]
// kv layout: row (b*8192+n), 768 cols: k at g*192+h*48, v at 384+g*192+h*48
// grid = (32 bgh, 32 splits), block 256; each thread owns 9 (c,d) pairs.
// ---------------------------------------------------------------------------
__global__ __launch_bounds__(256) void attp_kernel(
    const bf16* __restrict__ kvb, float* __restrict__ attp)
{
    const int bgh = blockIdx.x, split = blockIdx.y;
    const int b = bgh >> 3, r = bgh & 7, g = r >> 2, h = r & 3;
    const int kcol = g * 192 + h * 48, vcol = 384 + g * 192 + h * 48;
    const float scale = 0.14433756729740643f;  // 48^-0.5
    __shared__ float Ks[64 * 48];
    __shared__ float Vs[64 * 48];
    const int tid = threadIdx.x;
    int cc[9], dd9[9];
    float acc[9];
    #pragma unroll
    for (int p = 0; p < 9; ++p) {
        int pid = tid + p * 256; cc[p] = pid / 48; dd9[p] = pid % 48; acc[p] = 0.f;
    }
    for (int chunk = 0; chunk < 4; ++chunk) {
        const int nbase = split * 256 + chunk * 64;
        for (int i = tid; i < 64 * 48; i += 256) {
            int row = i / 48, col = i % 48;
            size_t gi = (size_t)(b * 8192 + nbase + row) * 768;
            Ks[i] = scale * (float)kvb[gi + kcol + col];
            Vs[i] = (float)kvb[gi + vcol + col];
        }
        __syncthreads();
        for (int n = 0; n < 64; ++n) {
            const float* kr = &Ks[n * 48];
            const float* vr = &Vs[n * 48];
            #pragma unroll
            for (int p = 0; p < 9; ++p) acc[p] += kr[cc[p]] * vr[dd9[p]];
        }
        __syncthreads();
    }
    float* op = attp + ((size_t)bgh * 32 + split) * 2304;
    #pragma unroll
    for (int p = 0; p < 9; ++p) op[tid + p * 256] = acc[p];
}

// ---------------------------------------------------------------------------
// Attention part 2: reduce 32 splits, fp32 softmax over rows, cast to bf16.
// grid = 32 blocks (bgh), block 256.
// ---------------------------------------------------------------------------
__global__ __launch_bounds__(256) void attred_kernel(
    const float* __restrict__ attp, bf16* __restrict__ att)
{
    const int bgh = blockIdx.x, tid = threadIdx.x;
    __shared__ float s[2304];
    for (int i = tid; i < 2304; i += 256) {
        float a = 0.f;
        for (int sp = 0; sp < 32; ++sp) a += attp[((size_t)bgh * 32 + sp) * 2304 + i];
        s[i] = a;
    }
    __syncthreads();
    if (tid < 48) {
        const int base = tid * 48;
        float mx = -1e30f;
        for (int d = 0; d < 48; ++d) mx = fmaxf(mx, s[base + d]);
        float sum = 0.f;
        for (int d = 0; d < 48; ++d) sum += expf(s[base + d] - mx);
        float inv = 1.f / sum;
        for (int d = 0; d < 48; ++d)
            att[(size_t)bgh * 2304 + base + d] = __float2bfloat16(expf(s[base + d] - mx) * inv);
    }
}

// ---------------------------------------------------------------------------
// y[n,d] = sum_e att[d,e] * q[n, g*48+e], written with the faithful scrambled
// reshape: row' = b*8192 + (2h+g)*1024 + n/8, col' = (n%8)*48 + d.
// grid = 4096 (b * n0), block 384 (one thread per output col').
// ---------------------------------------------------------------------------
__global__ __launch_bounds__(384) void y_kernel(
    const bf16* __restrict__ q, const bf16* __restrict__ att, bf16* __restrict__ y)
{
    const int blk = blockIdx.x;
    const int b = blk >> 10, n0 = blk & 1023;
    const int tid = threadIdx.x;
    __shared__ float qs[8 * 96];
    __shared__ unsigned short as_[8 * 48 * 50];  // [h2g][d][e], stride 50 (pad)
    for (int i = tid; i < 8 * 96; i += 384) {
        int nl = i / 96, col = i % 96;
        qs[i] = (float)q[(size_t)(b * 8192 + n0 * 8 + nl) * 96 + col];
    }
    const unsigned short* attu = (const unsigned short*)att;
    for (int i = tid; i < 8 * 2304; i += 384) {
        int h2g = i / 2304, j = i % 2304, d = j / 48, e = j % 48;
        int g = h2g & 1, hh = h2g >> 1;
        as_[h2g * 2400 + d * 50 + e] = attu[(size_t)(b * 8 + g * 4 + hh) * 2304 + j];
    }
    __syncthreads();
    const int nl = tid / 48, d = tid % 48;
    #pragma unroll
    for (int h2g = 0; h2g < 8; ++h2g) {
        const int g = h2g & 1;
        const float* qp = &qs[nl * 96 + g * 48];
        const unsigned short* ap = &as_[h2g * 2400 + d * 50];
        float acc = 0.f;
        #pragma unroll 8
        for (int e = 0; e < 48; ++e) acc += qp[e] * bf2f(ap[e]);
        y[(size_t)(b * 8192 + h2g * 1024 + n0) * 384 + tid] = __float2bfloat16(acc);
    }
}

// ---------------------------------------------------------------------------
extern "C" void kernel_launch(void* const* d_in, const int* in_sizes, int n_in,
                              void* d_out, int out_size, void* d_ws, size_t ws_size,
                              hipStream_t stream)
{
    (void)in_sizes; (void)n_in; (void)out_size; (void)ws_size;
    const float* x      = (const float*)d_in[0];
    const float* cpe0_w = (const float*)d_in[2];
    const float* cpe0_b = (const float*)d_in[3];
    const float* cpe1_w = (const float*)d_in[4];
    const float* cpe1_b = (const float*)d_in[5];
    const float* n1g    = (const float*)d_in[6];
    const float* n1b    = (const float*)d_in[7];
    const float* q_w    = (const float*)d_in[8];
    const float* kv_w   = (const float*)d_in[9];
    const float* proj_w = (const float*)d_in[10];
    const float* proj_b = (const float*)d_in[11];
    const float* n2g    = (const float*)d_in[12];
    const float* n2b    = (const float*)d_in[13];
    const float* w1     = (const float*)d_in[14];
    const float* b1     = (const float*)d_in[15];
    const float* w2     = (const float*)d_in[16];
    const float* b2     = (const float*)d_in[17];

    char* ws = (char*)d_ws;
    float* xf   = (float*)(ws + 0);           // 48 MB  residual stream fp32
    bf16*  t    = (bf16*)(ws + 50331648);     // 24 MB  LN output bf16
    char*  Cr   =         ws + 75497472;      // 48 MB  kv -> xf2 -> mlp acc
    bf16*  kvb  = (bf16*)Cr;
    float* xf2  = (float*)Cr;
    float* accO = (float*)Cr;
    bf16*  q    = (bf16*)(ws + 125829120);    //  6 MB
    float* attp = (float*)(ws + 132120576);   //  9 MB
    bf16*  att  = (bf16*)(ws + 141557760);    //  144 KB
    bf16*  yb   = (bf16*)(ws + 141705216);    // 32 MB  y -> h1 chunk
    bf16*  h1   = yb;
    // bf16 weights + transposed conv weights
    bf16*  qwb  = (bf16*)(ws + 175259648);    //  73,728 B
    bf16*  kvwb = (bf16*)(ws + 175333376);    // 589,824 B
    bf16*  pwb  = (bf16*)(ws + 175923200);    // 294,912 B
    bf16*  w1b  = (bf16*)(ws + 176218112);    // 1,179,648 B
    bf16*  w2b  = (bf16*)(ws + 177397760);    // 1,179,648 B
    float* wt0  = (float*)(ws + 178577408);   // 41,472 B
    float* wt1  = (float*)(ws + 178618880);   // 41,472 B

    const int NTOK = 32768;

    // 0. prep: weight conversions (bf16) + conv-weight transpose
    f2b_kernel<<<dim3(144), dim3(256), 0, stream>>>(q_w, qwb, 36864);
    f2b_kernel<<<dim3(576), dim3(256), 0, stream>>>(kv_w, kvwb, 294912);
    f2b_kernel<<<dim3(576), dim3(256), 0, stream>>>(proj_w, pwb, 147456);
    f2b_kernel<<<dim3(576), dim3(256), 0, stream>>>(w1, w1b, 589824);
    f2b_kernel<<<dim3(576), dim3(256), 0, stream>>>(w2, w2b, 589824);
    wtr_kernel<<<dim3(41), dim3(256), 0, stream>>>(cpe0_w, wt0, cpe1_w, wt1);

    // 1. CPE0: xf = x + dwconv(x) + b   (fp32)
    cpe_kernel<<<dim3(8192), dim3(384), 0, stream>>>(x, wt0, cpe0_b, xf);
    // 2. LN1: t = LN(xf)
    ln_kernel<<<dim3(NTOK / 4), dim3(256), 0, stream>>>(xf, n1g, n1b, t);
    // 3/4. q and kv projections (bf16 out)
    gemm_kernel<<<dim3(2, 512), dim3(256), 0, stream>>>(t, qwb, 96, q, nullptr, nullptr, 96, 384, 0);
    gemm_kernel<<<dim3(12, 512), dim3(256), 0, stream>>>(t, kvwb, 768, kvb, nullptr, nullptr, 768, 384, 0);
    // 5/6. channel attention scores + softmax
    attp_kernel<<<dim3(32, 32), dim3(256), 0, stream>>>(kvb, attp);
    attred_kernel<<<dim3(32), dim3(256), 0, stream>>>(attp, att);
    // 7. y = q @ att^T with scrambled reshape
    y_kernel<<<dim3(4096), dim3(384), 0, stream>>>(q, att, yb);
    // 8. proj: xf2 = y @ proj_w + proj_b + xf   (fp32)
    gemm_kernel<<<dim3(6, 512), dim3(256), 0, stream>>>(yb, pwb, 384, xf2, xf, proj_b, 384, 384, 2);
    // 9. CPE1: xf(=xf3) = xf2 + dwconv(xf2) + b
    cpe_kernel<<<dim3(8192), dim3(384), 0, stream>>>(xf2, wt1, cpe1_b, xf);
    // 10. LN2: t = LN(xf3)
    ln_kernel<<<dim3(NTOK / 4), dim3(256), 0, stream>>>(xf, n2g, n2b, t);
    // 11. MLP in 3 K-chunks of 512: out = xf3 + b2 + sum_j gelu(t@W1_j+b1_j)@W2_j
    for (int j = 0; j < 3; ++j) {
        gemm_kernel<<<dim3(8, 512), dim3(256), 0, stream>>>(
            t, w1b + j * 512, 1536, h1, nullptr, b1 + j * 512, 512, 384, 1);
        gemm_kernel<<<dim3(6, 512), dim3(256), 0, stream>>>(
            h1, w2b + (size_t)j * 512 * 384, 384,
            (j == 2) ? (void*)d_out : (void*)accO,
            j == 0 ? xf : accO, j == 0 ? b2 : nullptr, 384, 512, 2);
    }
}

// Round 4
// 809.831 us; speedup vs baseline: 2.6283x; 1.4382x over previous
//
#include <hip/hip_runtime.h>
#include <hip/hip_bf16.h>
#include <math.h>

using bf16 = __hip_bfloat16;
typedef __attribute__((ext_vector_type(8))) short s16x8;
typedef __attribute__((ext_vector_type(4))) float f32x4;

#define GLD16(g, l) __builtin_amdgcn_global_load_lds( \
    (const __attribute__((address_space(1))) unsigned int*)(const void*)(g), \
    (__attribute__((address_space(3))) unsigned int*)(void*)(l), 16, 0, 0)

// ---------------------------------------------------------------------------
// prep: W[K][N] fp32 -> WT[Npad][K] bf16 (rows n >= N zero-filled)
// ---------------------------------------------------------------------------
__global__ __launch_bounds__(256) void wtb_kernel(
    const float* __restrict__ src, bf16* __restrict__ dst, int K, int N, int Npad)
{
    int i = blockIdx.x * 256 + threadIdx.x;
    if (i < Npad * K) {
        int n = i / K, k = i % K;
        dst[i] = (n < N) ? __float2bfloat16(src[k * N + n]) : __float2bfloat16(0.f);
    }
}

// prep: conv weight transpose [384][27] -> [27][384]
__global__ __launch_bounds__(256) void wtr_kernel(
    const float* __restrict__ w0, float* __restrict__ t0,
    const float* __restrict__ w1, float* __restrict__ t1)
{
    int i = blockIdx.x * 256 + threadIdx.x;
    if (i < 384 * 27) {
        int c = i / 27, tap = i % 27;
        t0[tap * 384 + c] = w0[i];
        t1[tap * 384 + c] = w1[i];
    }
}

// ---------------------------------------------------------------------------
// Depthwise 3x3x3 conv + bias + residual, sliding-window: each thread makes
// 8 consecutive-w outputs for one channel-quad. block 384 = 96 quads x 4 wsegs.
// grid = 1024 (b,d,h rows). wgtT layout [27][384].
// ---------------------------------------------------------------------------
__global__ __launch_bounds__(384) void cpe_kernel(
    const float* __restrict__ src, const float* __restrict__ wgtT,
    const float* __restrict__ bias, float* __restrict__ out)
{
    const int tid = threadIdx.x;
    const int qd = tid % 96, c = qd * 4;
    const int wseg = tid / 96, w_base = wseg * 8;
    const int blk = blockIdx.x;
    const int h = blk & 31, d = (blk >> 5) & 7, b = blk >> 8;

    const float4 bv = *(const float4*)(bias + c);
    float4 acc[8];
    #pragma unroll
    for (int o = 0; o < 8; ++o) acc[o] = bv;

    #pragma unroll
    for (int kd = 0; kd < 3; ++kd) {
        const int dd = d + kd - 1;
        if ((unsigned)dd >= 8u) continue;          // block-uniform
        #pragma unroll
        for (int kh = 0; kh < 3; ++kh) {
            const int hh = h + kh - 1;
            if ((unsigned)hh >= 32u) continue;     // block-uniform
            const int tap0 = kd * 9 + kh * 3;
            const float4 w0 = *(const float4*)(wgtT + (tap0 + 0) * 384 + c);
            const float4 w1 = *(const float4*)(wgtT + (tap0 + 1) * 384 + c);
            const float4 w2 = *(const float4*)(wgtT + (tap0 + 2) * 384 + c);
            const float* rowp = src + ((((size_t)b * 8 + dd) * 32 + hh) * 32) * 384 + c;
            #pragma unroll
            for (int p = 0; p < 10; ++p) {
                const int ww = w_base + p - 1;
                const float m = ((unsigned)ww < 32u) ? 1.f : 0.f;
                const int wwc = min(max(ww, 0), 31);
                float4 sv = *(const float4*)(rowp + (size_t)wwc * 384);
                sv.x *= m; sv.y *= m; sv.z *= m; sv.w *= m;
                if (p < 8) {                       // kw=0 -> o=p
                    acc[p].x += sv.x * w0.x; acc[p].y += sv.y * w0.y;
                    acc[p].z += sv.z * w0.z; acc[p].w += sv.w * w0.w;
                }
                if (p >= 1 && p <= 8) {            // kw=1 -> o=p-1
                    acc[p-1].x += sv.x * w1.x; acc[p-1].y += sv.y * w1.y;
                    acc[p-1].z += sv.z * w1.z; acc[p-1].w += sv.w * w1.w;
                }
                if (p >= 2) {                      // kw=2 -> o=p-2
                    acc[p-2].x += sv.x * w2.x; acc[p-2].y += sv.y * w2.y;
                    acc[p-2].z += sv.z * w2.z; acc[p-2].w += sv.w * w2.w;
                }
            }
        }
    }
    const float* selfrow = src + ((((size_t)b * 8 + d) * 32 + h) * 32) * 384 + c;
    float* outrow = out + ((((size_t)b * 8 + d) * 32 + h) * 32) * 384 + c;
    #pragma unroll
    for (int o = 0; o < 8; ++o) {
        const size_t off = (size_t)(w_base + o) * 384;
        const float4 s0 = *(const float4*)(selfrow + off);
        float4 r;
        r.x = s0.x + acc[o].x; r.y = s0.y + acc[o].y;
        r.z = s0.z + acc[o].z; r.w = s0.w + acc[o].w;
        *(float4*)(outrow + off) = r;
    }
}

// ---------------------------------------------------------------------------
// LayerNorm over C=384, fp32 in, bf16 out.  One wave per token, 4 tokens/block.
// ---------------------------------------------------------------------------
__global__ __launch_bounds__(256) void ln_kernel(
    const float* __restrict__ src, const float* __restrict__ gam,
    const float* __restrict__ bet, bf16* __restrict__ out)
{
    const int wid = threadIdx.x >> 6, lane = threadIdx.x & 63;
    const int token = blockIdx.x * 4 + wid;
    const float* p = src + (size_t)token * 384;
    float v[6], s = 0.f, s2 = 0.f;
    #pragma unroll
    for (int i = 0; i < 6; ++i) { v[i] = p[lane + i * 64]; s += v[i]; s2 += v[i] * v[i]; }
    #pragma unroll
    for (int m = 1; m < 64; m <<= 1) { s += __shfl_xor(s, m); s2 += __shfl_xor(s2, m); }
    const float mean = s * (1.f / 384.f);
    const float var  = s2 * (1.f / 384.f) - mean * mean;
    const float rinv = rsqrtf(var + 1e-5f);
    bf16* o = out + (size_t)token * 384;
    #pragma unroll
    for (int i = 0; i < 6; ++i) {
        int cc = lane + i * 64;
        o[cc] = __float2bfloat16((v[i] - mean) * rinv * gam[cc] + bet[cc]);
    }
}

// ---------------------------------------------------------------------------
// GEMM (m97-style): out[M,N] = A[M,K](bf16) @ BT[N,K]^T(bf16)
// 128x128 tile, BK=64, block 256 = 4 waves (2x2), global_load_lds width 16.
// flags: 1 = gelu (exact erf), 2 = fp32 out.  res fp32 or null (ld = ldo).
// grid = (Npad/128, M/128).  Staging assumes BT has Npad rows (zero-padded).
// ---------------------------------------------------------------------------
__global__ __launch_bounds__(256) void gemm128_kernel(
    const bf16* __restrict__ A, int lda,
    const bf16* __restrict__ BT, int ldb,
    void* outp, int ldo, const float* res, const float* __restrict__ bias,
    int Nout, int K, int flags)
{
    __shared__ unsigned short As[128 * 64];
    __shared__ unsigned short Bs[128 * 64];
    const int tid = threadIdx.x;
    const int wid = tid >> 6, lane = tid & 63;
    const int m0 = blockIdx.y * 128, n0 = blockIdx.x * 128;
    const int moff = (wid >> 1) * 64, noff = (wid & 1) * 64;
    const int lrow = lane & 15, lk = (lane >> 4) * 8;
    const int srow = (lane >> 3), scol = (lane & 7) * 8;  // staging: 8 rows/KB

    f32x4 acc[4][4] = {};

    for (int k0 = 0; k0 < K; k0 += 64) {
        #pragma unroll
        for (int j = 0; j < 4; ++j) {
            const int r = (wid * 4 + j) * 8 + srow;
            GLD16(A + (size_t)(m0 + r) * lda + k0 + scol, As + (wid * 4 + j) * 512);
        }
        #pragma unroll
        for (int j = 0; j < 4; ++j) {
            const int r = (wid * 4 + j) * 8 + srow;
            GLD16(BT + (size_t)(n0 + r) * ldb + k0 + scol, Bs + (wid * 4 + j) * 512);
        }
        __syncthreads();
        #pragma unroll
        for (int ks = 0; ks < 64; ks += 32) {
            s16x8 af[4], bfr[4];
            #pragma unroll
            for (int i = 0; i < 4; ++i)
                af[i] = *(const s16x8*)(As + (moff + i * 16 + lrow) * 64 + ks + lk);
            #pragma unroll
            for (int i = 0; i < 4; ++i)
                bfr[i] = *(const s16x8*)(Bs + (noff + i * 16 + lrow) * 64 + ks + lk);
            #pragma unroll
            for (int mi = 0; mi < 4; ++mi)
                #pragma unroll
                for (int ni = 0; ni < 4; ++ni)
                    acc[mi][ni] = __builtin_amdgcn_mfma_f32_16x16x32_bf16(
                        af[mi], bfr[ni], acc[mi][ni], 0, 0, 0);
        }
        __syncthreads();
    }

    const bool gelu  = (flags & 1) != 0;
    const bool ofp32 = (flags & 2) != 0;
    const int rbase = (lane >> 4) * 4;
    #pragma unroll
    for (int mi = 0; mi < 4; ++mi) {
        #pragma unroll
        for (int ni = 0; ni < 4; ++ni) {
            const int gn = n0 + noff + ni * 16 + lrow;
            if (gn >= Nout) continue;
            const float bval = bias ? bias[gn] : 0.f;
            #pragma unroll
            for (int r = 0; r < 4; ++r) {
                const int gm = m0 + moff + mi * 16 + rbase + r;
                float v = acc[mi][ni][r] + bval;
                if (gelu) v = 0.5f * v * (1.f + erff(v * 0.70710678118f));
                if (res)  v += res[(size_t)gm * ldo + gn];
                if (ofp32) ((float*)outp)[(size_t)gm * ldo + gn] = v;
                else       ((bf16*)outp)[(size_t)gm * ldo + gn] = __float2bfloat16(v);
            }
        }
    }
}

// ---------------------------------------------------------------------------
// Attention scores via MFMA: partial[c,d] = sum_{n in split} K[n,c]*V[n,d]
// (scale applied at write).  grid (32 bgh, 32 splits), block 64 (1 wave).
// ---------------------------------------------------------------------------
__global__ __launch_bounds__(64) void attp_kernel(
    const bf16* __restrict__ kvb, float* __restrict__ attp)
{
    const int bgh = blockIdx.x, split = blockIdx.y;
    const int b = bgh >> 3, rr = bgh & 7, g = rr >> 2, h = rr & 3;
    const int kcol = g * 192 + h * 48, vcol = 384 + g * 192 + h * 48;
    __shared__ unsigned short Ks[256 * 48];
    __shared__ unsigned short Vs[256 * 48];
    const int lane = threadIdx.x;

    const size_t rowbase = (size_t)(b * 8192 + split * 256) * 768;
    for (int i = lane; i < 256 * 6; i += 64) {
        const int row = i / 6, part = i % 6;
        const size_t gi = rowbase + (size_t)row * 768;
        *(uint4*)(Ks + row * 48 + part * 8) = *(const uint4*)(kvb + gi + kcol + part * 8);
        *(uint4*)(Vs + row * 48 + part * 8) = *(const uint4*)(kvb + gi + vcol + part * 8);
    }
    __syncthreads();

    f32x4 acc[3][3] = {};
    const int col = lane & 15, kb = (lane >> 4) * 8;
    for (int ks = 0; ks < 256; ks += 32) {
        s16x8 af[3], bfr[3];
        #pragma unroll
        for (int t3 = 0; t3 < 3; ++t3) {
            #pragma unroll
            for (int j = 0; j < 8; ++j) {
                const int tok = ks + kb + j;
                af[t3][j]  = (short)Ks[tok * 48 + t3 * 16 + col];
                bfr[t3][j] = (short)Vs[tok * 48 + t3 * 16 + col];
            }
        }
        #pragma unroll
        for (int ct = 0; ct < 3; ++ct)
            #pragma unroll
            for (int dt = 0; dt < 3; ++dt)
                acc[ct][dt] = __builtin_amdgcn_mfma_f32_16x16x32_bf16(
                    af[ct], bfr[dt], acc[ct][dt], 0, 0, 0);
    }
    const float scale = 0.14433756729740643f;  // 48^-0.5
    float* op = attp + ((size_t)bgh * 32 + split) * 2304;
    const int rbase = (lane >> 4) * 4;
    #pragma unroll
    for (int ct = 0; ct < 3; ++ct)
        #pragma unroll
        for (int dt = 0; dt < 3; ++dt)
            #pragma unroll
            for (int r = 0; r < 4; ++r)
                op[(ct * 16 + rbase + r) * 48 + dt * 16 + col] = scale * acc[ct][dt][r];
}

// ---------------------------------------------------------------------------
// reduce 32 splits, fp32 softmax over rows, cast to bf16. grid 32, block 256.
// ---------------------------------------------------------------------------
__global__ __launch_bounds__(256) void attred_kernel(
    const float* __restrict__ attp, bf16* __restrict__ att)
{
    const int bgh = blockIdx.x, tid = threadIdx.x;
    __shared__ float s[2304];
    for (int i = tid; i < 2304; i += 256) {
        float a = 0.f;
        for (int sp = 0; sp < 32; ++sp) a += attp[((size_t)bgh * 32 + sp) * 2304 + i];
        s[i] = a;
    }
    __syncthreads();
    if (tid < 48) {
        const int base = tid * 48;
        float mx = -1e30f;
        for (int d = 0; d < 48; ++d) mx = fmaxf(mx, s[base + d]);
        float sum = 0.f;
        for (int d = 0; d < 48; ++d) sum += expf(s[base + d] - mx);
        float inv = 1.f / sum;
        for (int d = 0; d < 48; ++d)
            att[(size_t)bgh * 2304 + base + d] = __float2bfloat16(expf(s[base + d] - mx) * inv);
    }
}

// ---------------------------------------------------------------------------
// y = Q_g(8192x48) @ att^T(48x48) per (b,h2g), MFMA, K=48 padded to 64.
// Scrambled write: row' = b*8192 + h2g*1024 + n/8, col' = (n%8)*48 + d.
// grid (64 mtiles, 32 b*8+h2g), block 256 (4 waves x 32 rows).
// ---------------------------------------------------------------------------
__global__ __launch_bounds__(256) void y_kernel(
    const bf16* __restrict__ q, const bf16* __restrict__ att, bf16* __restrict__ y)
{
    const int m0 = blockIdx.x * 128;
    const int b = blockIdx.y >> 3, h2g = blockIdx.y & 7;
    const int g = h2g & 1, hh = h2g >> 1;
    const int bgh = b * 8 + g * 4 + hh;
    const int tid = threadIdx.x, wid = tid >> 6, lane = tid & 63;
    __shared__ unsigned short Qs[128 * 64];
    __shared__ unsigned short Ats[48 * 64];

    for (int i = tid; i < 128 * 6; i += 256) {
        const int row = i / 6, part = i % 6;
        *(uint4*)(Qs + row * 64 + part * 8) =
            *(const uint4*)(q + (size_t)(b * 8192 + m0 + row) * 96 + g * 48 + part * 8);
    }
    {
        const int row = tid / 2, half = tid & 1;   // 256 threads -> 128 rows x 2
        *(uint4*)(Qs + row * 64 + 48 + half * 8) = make_uint4(0, 0, 0, 0);
    }
    for (int i = tid; i < 48 * 6; i += 256) {
        const int row = i / 6, part = i % 6;
        *(uint4*)(Ats + row * 64 + part * 8) =
            *(const uint4*)(att + (size_t)bgh * 2304 + row * 48 + part * 8);
    }
    for (int i = tid; i < 96; i += 256) {
        const int row = i / 2, half = i & 1;
        *(uint4*)(Ats + row * 64 + 48 + half * 8) = make_uint4(0, 0, 0, 0);
    }
    __syncthreads();

    const int moff = wid * 32;
    const int col = lane & 15, kb = (lane >> 4) * 8;
    f32x4 acc[2][3] = {};
    #pragma unroll
    for (int ks = 0; ks < 64; ks += 32) {
        s16x8 af[2], bfr[3];
        #pragma unroll
        for (int mt = 0; mt < 2; ++mt)
            af[mt] = *(const s16x8*)(Qs + (moff + mt * 16 + col) * 64 + ks + kb);
        #pragma unroll
        for (int nt = 0; nt < 3; ++nt)
            bfr[nt] = *(const s16x8*)(Ats + (nt * 16 + col) * 64 + ks + kb);
        #pragma unroll
        for (int mt = 0; mt < 2; ++mt)
            #pragma unroll
            for (int nt = 0; nt < 3; ++nt)
                acc[mt][nt] = __builtin_amdgcn_mfma_f32_16x16x32_bf16(
                    af[mt], bfr[nt], acc[mt][nt], 0, 0, 0);
    }
    const int rbase = (lane >> 4) * 4;
    #pragma unroll
    for (int mt = 0; mt < 2; ++mt) {
        #pragma unroll
        for (int nt = 0; nt < 3; ++nt) {
            const int d = nt * 16 + col;
            #pragma unroll
            for (int r = 0; r < 4; ++r) {
                const int n = m0 + moff + mt * 16 + rbase + r;
                y[((size_t)b * 8192 + h2g * 1024 + (n >> 3)) * 384 + (n & 7) * 48 + d] =
                    __float2bfloat16(acc[mt][nt][r]);
            }
        }
    }
}

// ---------------------------------------------------------------------------
extern "C" void kernel_launch(void* const* d_in, const int* in_sizes, int n_in,
                              void* d_out, int out_size, void* d_ws, size_t ws_size,
                              hipStream_t stream)
{
    (void)in_sizes; (void)n_in; (void)out_size; (void)ws_size;
    const float* x      = (const float*)d_in[0];
    const float* cpe0_w = (const float*)d_in[2];
    const float* cpe0_b = (const float*)d_in[3];
    const float* cpe1_w = (const float*)d_in[4];
    const float* cpe1_b = (const float*)d_in[5];
    const float* n1g    = (const float*)d_in[6];
    const float* n1b    = (const float*)d_in[7];
    const float* q_w    = (const float*)d_in[8];
    const float* kv_w   = (const float*)d_in[9];
    const float* proj_w = (const float*)d_in[10];
    const float* proj_b = (const float*)d_in[11];
    const float* n2g    = (const float*)d_in[12];
    const float* n2b    = (const float*)d_in[13];
    const float* w1     = (const float*)d_in[14];
    const float* b1     = (const float*)d_in[15];
    const float* w2     = (const float*)d_in[16];
    const float* b2     = (const float*)d_in[17];

    char* ws = (char*)d_ws;
    // weights region (persistent through the launch)
    bf16*  qwT  = (bf16*)(ws + 0);          // [128][384]  98,304 B
    bf16*  kvwT = (bf16*)(ws + 98304);      // [768][384]  589,824 B
    bf16*  pwT  = (bf16*)(ws + 688128);     // [384][384]  294,912 B
    bf16*  w1T  = (bf16*)(ws + 983040);     // [1536][384] 1,179,648 B
    bf16*  w2T  = (bf16*)(ws + 2162688);    // [384][1536] 1,179,648 B
    float* wt0  = (float*)(ws + 3342336);   // [27][384]   41,472 B
    float* wt1  = (float*)(ws + 3383808);   // [27][384]   41,472 B
    // dynamic buffers
    float* xf   = (float*)(ws + 4194304);    // 48 MiB residual1 (later accO)
    bf16*  t    = (bf16*)(ws + 54525952);    // 24 MiB LN out
    bf16*  kv   = (bf16*)(ws + 79691776);    // 48 MiB [32768][768] (later xf3)
    bf16*  qb   = (bf16*)(ws + 130023424);   //  6 MiB [32768][96]  (later h1)
    float* attp = (float*)(ws + 136314880);  //  9 MiB
    bf16*  att  = (bf16*)(ws + 145752064);   //  144 KiB
    bf16*  yb   = (bf16*)(ws + 145899520);   // 24 MiB [32768][384]
    float* xf3  = (float*)(ws + 79691776);   // alias kv (dead after y/proj)
    bf16*  h1   = (bf16*)(ws + 130023424);   // alias qb..yb (32 MiB chunk)
    float* accO = (float*)(ws + 4194304);    // alias xf (dead after cpe1)

    // 0. prep: weight transposes
    wtb_kernel<<<dim3(192),  dim3(256), 0, stream>>>(q_w,    qwT,  384, 96,  128);
    wtb_kernel<<<dim3(1152), dim3(256), 0, stream>>>(kv_w,   kvwT, 384, 768, 768);
    wtb_kernel<<<dim3(576),  dim3(256), 0, stream>>>(proj_w, pwT,  384, 384, 384);
    wtb_kernel<<<dim3(2304), dim3(256), 0, stream>>>(w1,     w1T,  384, 1536, 1536);
    wtb_kernel<<<dim3(2304), dim3(256), 0, stream>>>(w2,     w2T,  1536, 384, 384);
    wtr_kernel<<<dim3(41),   dim3(256), 0, stream>>>(cpe0_w, wt0, cpe1_w, wt1);

    // 1. CPE0: xf = x + dwconv(x) + b
    cpe_kernel<<<dim3(1024), dim3(384), 0, stream>>>(x, wt0, cpe0_b, xf);
    // 2. LN1
    ln_kernel<<<dim3(8192), dim3(256), 0, stream>>>(xf, n1g, n1b, t);
    // 3/4. q and kv projections
    gemm128_kernel<<<dim3(1, 256), dim3(256), 0, stream>>>(
        t, 384, qwT, 384, qb, 96, nullptr, nullptr, 96, 384, 0);
    gemm128_kernel<<<dim3(6, 256), dim3(256), 0, stream>>>(
        t, 384, kvwT, 384, kv, 768, nullptr, nullptr, 768, 384, 0);
    // 5/6. channel-attention scores (MFMA split-K) + softmax
    attp_kernel<<<dim3(32, 32), dim3(64), 0, stream>>>(kv, attp);
    attred_kernel<<<dim3(32), dim3(256), 0, stream>>>(attp, att);
    // 7. y = q @ att^T (MFMA) with scrambled reshape
    y_kernel<<<dim3(64, 32), dim3(256), 0, stream>>>(qb, att, yb);
    // 8. proj (in-place residual): xf = yb @ proj_w + proj_b + xf
    gemm128_kernel<<<dim3(3, 256), dim3(256), 0, stream>>>(
        yb, 384, pwT, 384, xf, 384, xf, proj_b, 384, 384, 2);
    // 9. CPE1: xf3 = xf + dwconv(xf) + b
    cpe_kernel<<<dim3(1024), dim3(384), 0, stream>>>(xf, wt1, cpe1_b, xf3);
    // 10. LN2
    ln_kernel<<<dim3(8192), dim3(256), 0, stream>>>(xf3, n2g, n2b, t);
    // 11. MLP in 3 K-chunks of 512
    for (int j = 0; j < 3; ++j) {
        gemm128_kernel<<<dim3(4, 256), dim3(256), 0, stream>>>(
            t, 384, w1T + (size_t)j * 512 * 384, 384,
            h1, 512, nullptr, b1 + j * 512, 512, 384, 1);
        gemm128_kernel<<<dim3(3, 256), dim3(256), 0, stream>>>(
            h1, 512, w2T + j * 512, 1536,
            (j == 2) ? (void*)d_out : (void*)accO, 384,
            (j == 0) ? xf3 : accO, (j == 0) ? b2 : nullptr, 384, 512, 2);
    }
}

// Round 5
// 619.402 us; speedup vs baseline: 3.4364x; 1.3074x over previous
//
#include <hip/hip_runtime.h>
#include <hip/hip_bf16.h>
#include <math.h>

using bf16 = __hip_bfloat16;
typedef __attribute__((ext_vector_type(8))) short s16x8;
typedef __attribute__((ext_vector_type(4))) float f32x4;

__device__ __forceinline__ unsigned short f2bf(float f) {
    union { bf16 b; unsigned short u; } cv; cv.b = __float2bfloat16(f); return cv.u;
}

#define GLD16(g, l) __builtin_amdgcn_global_load_lds( \
    (const __attribute__((address_space(1))) unsigned int*)(const void*)(g), \
    (__attribute__((address_space(3))) unsigned int*)(void*)(l), 16, 0, 0)

// ---------------------------------------------------------------------------
// prep: W[K][N] fp32 -> WT[Npad][K] bf16 (rows n >= N zero-filled)
// ---------------------------------------------------------------------------
__global__ __launch_bounds__(256) void wtb_kernel(
    const float* __restrict__ src, bf16* __restrict__ dst, int K, int N, int Npad)
{
    int i = blockIdx.x * 256 + threadIdx.x;
    if (i < Npad * K) {
        int n = i / K, k = i % K;
        dst[i] = (n < N) ? __float2bfloat16(src[k * N + n]) : __float2bfloat16(0.f);
    }
}

// prep: conv weight transpose [384][27] -> [27][384]
__global__ __launch_bounds__(256) void wtr_kernel(
    const float* __restrict__ w0, float* __restrict__ t0,
    const float* __restrict__ w1, float* __restrict__ t1)
{
    int i = blockIdx.x * 256 + threadIdx.x;
    if (i < 384 * 27) {
        int c = i / 27, tap = i % 27;
        t0[tap * 384 + c] = w0[i];
        t1[tap * 384 + c] = w1[i];
    }
}

// ---------------------------------------------------------------------------
// Depthwise 3x3x3 conv + bias + residual + FUSED LayerNorm.
// Block = one (b,d,h) row: 32 tokens x 384 channels. 384 thr = 96 quads x 4 wsegs.
// Outputs: xf_out fp32 (pre-LN residual) and t_out bf16 (LN result).
// ---------------------------------------------------------------------------
__global__ __launch_bounds__(384) void cpe_ln_kernel(
    const float* __restrict__ src, const float* __restrict__ wgtT,
    const float* __restrict__ bias, const float* __restrict__ gam,
    const float* __restrict__ bet, float* __restrict__ xf_out,
    bf16* __restrict__ t_out)
{
    const int tid = threadIdx.x;
    const int qd = tid % 96, c = qd * 4;
    const int wseg = tid / 96, w_base = wseg * 8;
    const int blk = blockIdx.x;
    const int h = blk & 31, d = (blk >> 5) & 7, b = blk >> 8;

    const float4 bv = *(const float4*)(bias + c);
    float4 acc[8];
    #pragma unroll
    for (int o = 0; o < 8; ++o) acc[o] = bv;

    #pragma unroll
    for (int kd = 0; kd < 3; ++kd) {
        const int dd = d + kd - 1;
        if ((unsigned)dd >= 8u) continue;          // block-uniform
        #pragma unroll
        for (int kh = 0; kh < 3; ++kh) {
            const int hh = h + kh - 1;
            if ((unsigned)hh >= 32u) continue;     // block-uniform
            const int tap0 = kd * 9 + kh * 3;
            const float4 w0 = *(const float4*)(wgtT + (tap0 + 0) * 384 + c);
            const float4 w1 = *(const float4*)(wgtT + (tap0 + 1) * 384 + c);
            const float4 w2 = *(const float4*)(wgtT + (tap0 + 2) * 384 + c);
            const float* rowp = src + ((((size_t)b * 8 + dd) * 32 + hh) * 32) * 384 + c;
            #pragma unroll
            for (int p = 0; p < 10; ++p) {
                const int ww = w_base + p - 1;
                const float m = ((unsigned)ww < 32u) ? 1.f : 0.f;
                const int wwc = min(max(ww, 0), 31);
                float4 sv = *(const float4*)(rowp + (size_t)wwc * 384);
                sv.x *= m; sv.y *= m; sv.z *= m; sv.w *= m;
                if (p < 8) {
                    acc[p].x += sv.x * w0.x; acc[p].y += sv.y * w0.y;
                    acc[p].z += sv.z * w0.z; acc[p].w += sv.w * w0.w;
                }
                if (p >= 1 && p <= 8) {
                    acc[p-1].x += sv.x * w1.x; acc[p-1].y += sv.y * w1.y;
                    acc[p-1].z += sv.z * w1.z; acc[p-1].w += sv.w * w1.w;
                }
                if (p >= 2) {
                    acc[p-2].x += sv.x * w2.x; acc[p-2].y += sv.y * w2.y;
                    acc[p-2].z += sv.z * w2.z; acc[p-2].w += sv.w * w2.w;
                }
            }
        }
    }
    const size_t rowoff = ((((size_t)b * 8 + d) * 32 + h) * 32) * 384 + c;
    float4 r[8];
    __shared__ float2 part[32][96];
    #pragma unroll
    for (int o = 0; o < 8; ++o) {
        const size_t off = rowoff + (size_t)(w_base + o) * 384;
        const float4 s0 = *(const float4*)(src + off);
        r[o].x = s0.x + acc[o].x; r[o].y = s0.y + acc[o].y;
        r[o].z = s0.z + acc[o].z; r[o].w = s0.w + acc[o].w;
        *(float4*)(xf_out + off) = r[o];
        const float s = r[o].x + r[o].y + r[o].z + r[o].w;
        const float s2 = r[o].x*r[o].x + r[o].y*r[o].y + r[o].z*r[o].z + r[o].w*r[o].w;
        part[w_base + o][qd] = make_float2(s, s2);
    }
    __syncthreads();
    __shared__ float2 red[32][12];
    {
        const int tk = tid / 12, j = tid % 12;
        float s = 0.f, s2 = 0.f;
        #pragma unroll
        for (int u = 0; u < 8; ++u) {
            const float2 p = part[tk][j * 8 + u];
            s += p.x; s2 += p.y;
        }
        red[tk][j] = make_float2(s, s2);
    }
    __syncthreads();
    __shared__ float2 stats[32];
    if (tid < 32) {
        float s = 0.f, s2 = 0.f;
        #pragma unroll
        for (int j = 0; j < 12; ++j) { s += red[tid][j].x; s2 += red[tid][j].y; }
        const float mean = s * (1.f / 384.f);
        const float var = s2 * (1.f / 384.f) - mean * mean;
        stats[tid] = make_float2(mean, rsqrtf(var + 1e-5f));
    }
    __syncthreads();
    const float4 gv = *(const float4*)(gam + c);
    const float4 be = *(const float4*)(bet + c);
    #pragma unroll
    for (int o = 0; o < 8; ++o) {
        const int tk = w_base + o;
        const float2 st = stats[tk];
        ushort4 u;
        u.x = f2bf((r[o].x - st.x) * st.y * gv.x + be.x);
        u.y = f2bf((r[o].y - st.x) * st.y * gv.y + be.y);
        u.z = f2bf((r[o].z - st.x) * st.y * gv.z + be.z);
        u.w = f2bf((r[o].w - st.x) * st.y * gv.w + be.w);
        *(ushort4*)((unsigned short*)t_out + (size_t)(blk * 32 + tk) * 384 + c) = u;
    }
}

// ---------------------------------------------------------------------------
// GEMM (m97-style): out[M,N] = A[M,K](bf16) @ BT[N,K]^T(bf16)
// 128x128 tile, BK=64, block 256, global_load_lds w16, XOR-swizzled LDS:
// physical k-chunk = logical k-chunk ^ (row & 7)  -> conflict-free ds_read_b128.
// flags: 1 = gelu (exact erf), 2 = fp32 out.  res fp32 or null (ld = ldo).
// ---------------------------------------------------------------------------
__global__ __launch_bounds__(256) void gemm128_kernel(
    const bf16* __restrict__ A, int lda,
    const bf16* __restrict__ BT, int ldb,
    void* outp, int ldo, const float* res, const float* __restrict__ bias,
    int Nout, int K, int flags)
{
    __shared__ unsigned short As[128 * 64];
    __shared__ unsigned short Bs[128 * 64];
    const int tid = threadIdx.x;
    const int wid = tid >> 6, lane = tid & 63;
    const int m0 = blockIdx.y * 128, n0 = blockIdx.x * 128;
    const int moff = (wid >> 1) * 64, noff = (wid & 1) * 64;
    const int lrow = lane & 15, quad = lane >> 4;
    const int srow = lane >> 3;
    const int scol = ((lane & 7) ^ srow) * 8;     // swizzled source k-chunk
    const int sw = lrow & 7;                      // read-side row swizzle

    f32x4 acc[4][4] = {};

    for (int k0 = 0; k0 < K; k0 += 64) {
        #pragma unroll
        for (int j = 0; j < 4; ++j) {
            const int r = (wid * 4 + j) * 8 + srow;
            GLD16(A + (size_t)(m0 + r) * lda + k0 + scol, As + (wid * 4 + j) * 512);
        }
        #pragma unroll
        for (int j = 0; j < 4; ++j) {
            const int r = (wid * 4 + j) * 8 + srow;
            GLD16(BT + (size_t)(n0 + r) * ldb + k0 + scol, Bs + (wid * 4 + j) * 512);
        }
        __syncthreads();
        #pragma unroll
        for (int ks = 0; ks < 64; ks += 32) {
            const int kc = (ks >> 3) + quad;
            const int koff = ((kc ^ sw) << 3);
            s16x8 af[4], bfr[4];
            #pragma unroll
            for (int i = 0; i < 4; ++i)
                af[i] = *(const s16x8*)(As + (moff + i * 16 + lrow) * 64 + koff);
            #pragma unroll
            for (int i = 0; i < 4; ++i)
                bfr[i] = *(const s16x8*)(Bs + (noff + i * 16 + lrow) * 64 + koff);
            #pragma unroll
            for (int mi = 0; mi < 4; ++mi)
                #pragma unroll
                for (int ni = 0; ni < 4; ++ni)
                    acc[mi][ni] = __builtin_amdgcn_mfma_f32_16x16x32_bf16(
                        af[mi], bfr[ni], acc[mi][ni], 0, 0, 0);
        }
        __syncthreads();
    }

    const bool gelu  = (flags & 1) != 0;
    const bool ofp32 = (flags & 2) != 0;
    const int rbase = quad * 4;
    #pragma unroll
    for (int mi = 0; mi < 4; ++mi) {
        #pragma unroll
        for (int ni = 0; ni < 4; ++ni) {
            const int gn = n0 + noff + ni * 16 + lrow;
            if (gn >= Nout) continue;
            const float bval = bias ? bias[gn] : 0.f;
            #pragma unroll
            for (int r = 0; r < 4; ++r) {
                const int gm = m0 + moff + mi * 16 + rbase + r;
                float v = acc[mi][ni][r] + bval;
                if (gelu) v = 0.5f * v * (1.f + erff(v * 0.70710678118f));
                if (res)  v += res[(size_t)gm * ldo + gn];
                if (ofp32) ((float*)outp)[(size_t)gm * ldo + gn] = v;
                else       ((bf16*)outp)[(size_t)gm * ldo + gn] = __float2bfloat16(v);
            }
        }
    }
}

// ---------------------------------------------------------------------------
// Attention scores via MFMA: partial[c,d] = sum_{n in split} K[n,c]*V[n,d]
// (scale applied at write).  grid (32 bgh, 32 splits), block 64 (1 wave).
// ---------------------------------------------------------------------------
__global__ __launch_bounds__(64) void attp_kernel(
    const bf16* __restrict__ kvb, float* __restrict__ attp)
{
    const int bgh = blockIdx.x, split = blockIdx.y;
    const int b = bgh >> 3, rr = bgh & 7, g = rr >> 2, h = rr & 3;
    const int kcol = g * 192 + h * 48, vcol = 384 + g * 192 + h * 48;
    __shared__ unsigned short Ks[256 * 48];
    __shared__ unsigned short Vs[256 * 48];
    const int lane = threadIdx.x;

    const size_t rowbase = (size_t)(b * 8192 + split * 256) * 768;
    for (int i = lane; i < 256 * 6; i += 64) {
        const int row = i / 6, part = i % 6;
        const size_t gi = rowbase + (size_t)row * 768;
        *(uint4*)(Ks + row * 48 + part * 8) = *(const uint4*)(kvb + gi + kcol + part * 8);
        *(uint4*)(Vs + row * 48 + part * 8) = *(const uint4*)(kvb + gi + vcol + part * 8);
    }
    __syncthreads();

    f32x4 acc[3][3] = {};
    const int col = lane & 15, kb = (lane >> 4) * 8;
    for (int ks = 0; ks < 256; ks += 32) {
        s16x8 af[3], bfr[3];
        #pragma unroll
        for (int t3 = 0; t3 < 3; ++t3) {
            #pragma unroll
            for (int j = 0; j < 8; ++j) {
                const int tok = ks + kb + j;
                af[t3][j]  = (short)Ks[tok * 48 + t3 * 16 + col];
                bfr[t3][j] = (short)Vs[tok * 48 + t3 * 16 + col];
            }
        }
        #pragma unroll
        for (int ct = 0; ct < 3; ++ct)
            #pragma unroll
            for (int dt = 0; dt < 3; ++dt)
                acc[ct][dt] = __builtin_amdgcn_mfma_f32_16x16x32_bf16(
                    af[ct], bfr[dt], acc[ct][dt], 0, 0, 0);
    }
    const float scale = 0.14433756729740643f;  // 48^-0.5
    float* op = attp + ((size_t)bgh * 32 + split) * 2304;
    const int rbase = (lane >> 4) * 4;
    #pragma unroll
    for (int ct = 0; ct < 3; ++ct)
        #pragma unroll
        for (int dt = 0; dt < 3; ++dt)
            #pragma unroll
            for (int r = 0; r < 4; ++r)
                op[(ct * 16 + rbase + r) * 48 + dt * 16 + col] = scale * acc[ct][dt][r];
}

// ---------------------------------------------------------------------------
// reduce 32 splits, fp32 softmax over rows, cast to bf16. grid 32, block 256.
// ---------------------------------------------------------------------------
__global__ __launch_bounds__(256) void attred_kernel(
    const float* __restrict__ attp, bf16* __restrict__ att)
{
    const int bgh = blockIdx.x, tid = threadIdx.x;
    __shared__ float s[2304];
    for (int i = tid; i < 2304; i += 256) {
        float a = 0.f;
        for (int sp = 0; sp < 32; ++sp) a += attp[((size_t)bgh * 32 + sp) * 2304 + i];
        s[i] = a;
    }
    __syncthreads();
    if (tid < 48) {
        const int base = tid * 48;
        float mx = -1e30f;
        for (int d = 0; d < 48; ++d) mx = fmaxf(mx, s[base + d]);
        float sum = 0.f;
        for (int d = 0; d < 48; ++d) sum += expf(s[base + d] - mx);
        float inv = 1.f / sum;
        for (int d = 0; d < 48; ++d)
            att[(size_t)bgh * 2304 + base + d] = __float2bfloat16(expf(s[base + d] - mx) * inv);
    }
}

// ---------------------------------------------------------------------------
// y = Q_g(8192x48) @ att^T(48x48) per (b,h2g), MFMA, K=48 padded to 64.
// Scrambled write: row' = b*8192 + h2g*1024 + n/8, col' = (n%8)*48 + d.
// grid (64 mtiles, 32 b*8+h2g), block 256 (4 waves x 32 rows).
// ---------------------------------------------------------------------------
__global__ __launch_bounds__(256) void y_kernel(
    const bf16* __restrict__ q, const bf16* __restrict__ att, bf16* __restrict__ y)
{
    const int m0 = blockIdx.x * 128;
    const int b = blockIdx.y >> 3, h2g = blockIdx.y & 7;
    const int g = h2g & 1, hh = h2g >> 1;
    const int bgh = b * 8 + g * 4 + hh;
    const int tid = threadIdx.x, wid = tid >> 6, lane = tid & 63;
    __shared__ unsigned short Qs[128 * 64];
    __shared__ unsigned short Ats[48 * 64];

    for (int i = tid; i < 128 * 6; i += 256) {
        const int row = i / 6, part = i % 6;
        *(uint4*)(Qs + row * 64 + part * 8) =
            *(const uint4*)(q + (size_t)(b * 8192 + m0 + row) * 96 + g * 48 + part * 8);
    }
    {
        const int row = tid / 2, half = tid & 1;
        *(uint4*)(Qs + row * 64 + 48 + half * 8) = make_uint4(0, 0, 0, 0);
    }
    for (int i = tid; i < 48 * 6; i += 256) {
        const int row = i / 6, part = i % 6;
        *(uint4*)(Ats + row * 64 + part * 8) =
            *(const uint4*)(att + (size_t)bgh * 2304 + row * 48 + part * 8);
    }
    for (int i = tid; i < 96; i += 256) {
        const int row = i / 2, half = i & 1;
        *(uint4*)(Ats + row * 64 + 48 + half * 8) = make_uint4(0, 0, 0, 0);
    }
    __syncthreads();

    const int moff = wid * 32;
    const int col = lane & 15, kb = (lane >> 4) * 8;
    f32x4 acc[2][3] = {};
    #pragma unroll
    for (int ks = 0; ks < 64; ks += 32) {
        s16x8 af[2], bfr[3];
        #pragma unroll
        for (int mt = 0; mt < 2; ++mt)
            af[mt] = *(const s16x8*)(Qs + (moff + mt * 16 + col) * 64 + ks + kb);
        #pragma unroll
        for (int nt = 0; nt < 3; ++nt)
            bfr[nt] = *(const s16x8*)(Ats + (nt * 16 + col) * 64 + ks + kb);
        #pragma unroll
        for (int mt = 0; mt < 2; ++mt)
            #pragma unroll
            for (int nt = 0; nt < 3; ++nt)
                acc[mt][nt] = __builtin_amdgcn_mfma_f32_16x16x32_bf16(
                    af[mt], bfr[nt], acc[mt][nt], 0, 0, 0);
    }
    const int rbase = (lane >> 4) * 4;
    #pragma unroll
    for (int mt = 0; mt < 2; ++mt) {
        #pragma unroll
        for (int nt = 0; nt < 3; ++nt) {
            const int d = nt * 16 + col;
            #pragma unroll
            for (int r = 0; r < 4; ++r) {
                const int n = m0 + moff + mt * 16 + rbase + r;
                y[((size_t)b * 8192 + h2g * 1024 + (n >> 3)) * 384 + (n & 7) * 48 + d] =
                    __float2bfloat16(acc[mt][nt][r]);
            }
        }
    }
}

// ---------------------------------------------------------------------------
extern "C" void kernel_launch(void* const* d_in, const int* in_sizes, int n_in,
                              void* d_out, int out_size, void* d_ws, size_t ws_size,
                              hipStream_t stream)
{
    (void)in_sizes; (void)n_in; (void)out_size; (void)ws_size;
    const float* x      = (const float*)d_in[0];
    const float* cpe0_w = (const float*)d_in[2];
    const float* cpe0_b = (const float*)d_in[3];
    const float* cpe1_w = (const float*)d_in[4];
    const float* cpe1_b = (const float*)d_in[5];
    const float* n1g    = (const float*)d_in[6];
    const float* n1b    = (const float*)d_in[7];
    const float* q_w    = (const float*)d_in[8];
    const float* kv_w   = (const float*)d_in[9];
    const float* proj_w = (const float*)d_in[10];
    const float* proj_b = (const float*)d_in[11];
    const float* n2g    = (const float*)d_in[12];
    const float* n2b    = (const float*)d_in[13];
    const float* w1     = (const float*)d_in[14];
    const float* b1     = (const float*)d_in[15];
    const float* w2     = (const float*)d_in[16];
    const float* b2     = (const float*)d_in[17];

    char* ws = (char*)d_ws;
    // weights (persistent)
    bf16*  qwT  = (bf16*)(ws + 0);          // [128][384]
    bf16*  kvwT = (bf16*)(ws + 98304);      // [768][384]
    bf16*  pwT  = (bf16*)(ws + 688128);     // [384][384]
    bf16*  w1T  = (bf16*)(ws + 983040);     // [1536][384]
    bf16*  w2T  = (bf16*)(ws + 2162688);    // [384][1536]
    float* wt0  = (float*)(ws + 3342336);   // [27][384]
    float* wt1  = (float*)(ws + 3383808);   // [27][384]
    // dynamic buffers
    float* xf   = (float*)(ws + 4194304);    // 48 MiB residual1; later h1
    bf16*  t    = (bf16*)(ws + 54525952);    // 24 MiB LN out (t1 then t2)
    bf16*  kv   = (bf16*)(ws + 79691776);    // 48 MiB kv; later xf3
    bf16*  qb   = (bf16*)(ws + 130023424);   //  6 MiB
    float* attp = (float*)(ws + 136314880);  //  9 MiB
    bf16*  att  = (bf16*)(ws + 145752064);   //  144 KiB
    bf16*  yb   = (bf16*)(ws + 145899520);   // 24 MiB
    float* xf3  = (float*)(ws + 79691776);   // alias kv (dead after attp)
    bf16*  h1   = (bf16*)(ws + 4194304);     // alias xf (dead after cpe1)

    // 0. prep
    wtb_kernel<<<dim3(192),  dim3(256), 0, stream>>>(q_w,    qwT,  384, 96,  128);
    wtb_kernel<<<dim3(1152), dim3(256), 0, stream>>>(kv_w,   kvwT, 384, 768, 768);
    wtb_kernel<<<dim3(576),  dim3(256), 0, stream>>>(proj_w, pwT,  384, 384, 384);
    wtb_kernel<<<dim3(2304), dim3(256), 0, stream>>>(w1,     w1T,  384, 1536, 1536);
    wtb_kernel<<<dim3(2304), dim3(256), 0, stream>>>(w2,     w2T,  1536, 384, 384);
    wtr_kernel<<<dim3(41),   dim3(256), 0, stream>>>(cpe0_w, wt0, cpe1_w, wt1);

    // 1. CPE0 + LN1 fused: xf = x + dwconv(x) + b ; t = LN(xf)
    cpe_ln_kernel<<<dim3(1024), dim3(384), 0, stream>>>(x, wt0, cpe0_b, n1g, n1b, xf, t);
    // 2/3. q and kv projections
    gemm128_kernel<<<dim3(1, 256), dim3(256), 0, stream>>>(
        t, 384, qwT, 384, qb, 96, nullptr, nullptr, 96, 384, 0);
    gemm128_kernel<<<dim3(6, 256), dim3(256), 0, stream>>>(
        t, 384, kvwT, 384, kv, 768, nullptr, nullptr, 768, 384, 0);
    // 4/5. channel-attention scores (MFMA split-K) + softmax
    attp_kernel<<<dim3(32, 32), dim3(64), 0, stream>>>(kv, attp);
    attred_kernel<<<dim3(32), dim3(256), 0, stream>>>(attp, att);
    // 6. y = q @ att^T (MFMA) with scrambled reshape
    y_kernel<<<dim3(64, 32), dim3(256), 0, stream>>>(qb, att, yb);
    // 7. proj (in-place residual): xf = yb @ proj_w + proj_b + xf
    gemm128_kernel<<<dim3(3, 256), dim3(256), 0, stream>>>(
        yb, 384, pwT, 384, xf, 384, xf, proj_b, 384, 384, 2);
    // 8. CPE1 + LN2 fused: xf3 = xf + dwconv(xf) + b ; t = LN(xf3)
    cpe_ln_kernel<<<dim3(1024), dim3(384), 0, stream>>>(xf, wt1, cpe1_b, n2g, n2b, xf3, t);
    // 9. MLP in 2 M-halves, full-K (no partial-sum round trips):
    //    h1 = gelu(t@W1+b1); out = h1@W2 + b2 + xf3  (fp32 straight to d_out)
    for (int half = 0; half < 2; ++half) {
        const size_t mo = (size_t)half * 16384;
        gemm128_kernel<<<dim3(12, 128), dim3(256), 0, stream>>>(
            t + mo * 384, 384, w1T, 384, h1, 1536, nullptr, b1, 1536, 384, 1);
        gemm128_kernel<<<dim3(3, 128), dim3(256), 0, stream>>>(
            h1, 1536, w2T, 1536, (float*)d_out + mo * 384, 384,
            xf3 + mo * 384, b2, 384, 1536, 2);
    }
}

// Round 6
// 548.125 us; speedup vs baseline: 3.8833x; 1.1300x over previous
//
#include <hip/hip_runtime.h>
#include <hip/hip_bf16.h>
#include <math.h>

using bf16 = __hip_bfloat16;
typedef __attribute__((ext_vector_type(8))) short s16x8;
typedef __attribute__((ext_vector_type(4))) float f32x4;

__device__ __forceinline__ float bf2f(unsigned short u) {
    return __uint_as_float(((unsigned int)u) << 16);
}
__device__ __forceinline__ unsigned short f2bf(float f) {
    union { bf16 b; unsigned short u; } cv; cv.b = __float2bfloat16(f); return cv.u;
}
__device__ __forceinline__ float4 ld4(const float* p) { return *(const float4*)p; }
__device__ __forceinline__ float4 ld4(const bf16* p) {
    ushort4 u = *(const ushort4*)p;
    return make_float4(bf2f(u.x), bf2f(u.y), bf2f(u.z), bf2f(u.w));
}

#define GLD16(g, l) __builtin_amdgcn_global_load_lds( \
    (const __attribute__((address_space(1))) unsigned int*)(const void*)(g), \
    (__attribute__((address_space(3))) unsigned int*)(void*)(l), 16, 0, 0)

// ---------------------------------------------------------------------------
// merged prep: all weight transposes in one dispatch (index-range segmented)
// ---------------------------------------------------------------------------
__device__ __forceinline__ void wtbT(const float* __restrict__ src,
                                     bf16* __restrict__ dst, int K, int N, int i)
{
    int n = i / K, k = i % K;
    dst[i] = (n < N) ? __float2bfloat16(src[k * N + n]) : __float2bfloat16(0.f);
}

__global__ __launch_bounds__(256) void prep_kernel(
    const float* q_w, const float* kv_w, const float* proj_w,
    const float* w1, const float* w2,
    const float* cpe0_w, const float* cpe1_w,
    bf16* qwT, bf16* kvwT, bf16* pwT, bf16* w1T, bf16* w2T,
    float* wt0, float* wt1)
{
    int i = blockIdx.x * 256 + threadIdx.x;
    if      (i < 49152)   wtbT(q_w,    qwT,  384, 96,   i);
    else if (i < 344064)  wtbT(kv_w,   kvwT, 384, 768,  i - 49152);
    else if (i < 491520)  wtbT(proj_w, pwT,  384, 384,  i - 344064);
    else if (i < 1081344) wtbT(w1,     w1T,  384, 1536, i - 491520);
    else if (i < 1671168) wtbT(w2,     w2T,  1536, 384, i - 1081344);
    else if (i < 1681536) { int j = i - 1671168; wt0[(j % 27) * 384 + j / 27] = cpe0_w[j]; }
    else if (i < 1691904) { int j = i - 1681536; wt1[(j % 27) * 384 + j / 27] = cpe1_w[j]; }
}

// ---------------------------------------------------------------------------
// Depthwise 3x3x3 conv + bias + residual + FUSED LayerNorm.
// Block = one (b,d,h) row: 32 tokens x 384 ch. src fp32 or bf16 (templated);
// xf_out bf16 (pre-LN residual), t_out bf16 (LN result).
// ---------------------------------------------------------------------------
template <typename T>
__global__ __launch_bounds__(384) void cpe_ln_kernel(
    const T* __restrict__ src, const float* __restrict__ wgtT,
    const float* __restrict__ bias, const float* __restrict__ gam,
    const float* __restrict__ bet, bf16* __restrict__ xf_out,
    bf16* __restrict__ t_out)
{
    const int tid = threadIdx.x;
    const int qd = tid % 96, c = qd * 4;
    const int wseg = tid / 96, w_base = wseg * 8;
    const int blk = blockIdx.x;
    const int h = blk & 31, d = (blk >> 5) & 7, b = blk >> 8;

    const float4 bv = *(const float4*)(bias + c);
    float4 acc[8];
    #pragma unroll
    for (int o = 0; o < 8; ++o) acc[o] = bv;

    #pragma unroll
    for (int kd = 0; kd < 3; ++kd) {
        const int dd = d + kd - 1;
        if ((unsigned)dd >= 8u) continue;
        #pragma unroll
        for (int kh = 0; kh < 3; ++kh) {
            const int hh = h + kh - 1;
            if ((unsigned)hh >= 32u) continue;
            const int tap0 = kd * 9 + kh * 3;
            const float4 w0 = *(const float4*)(wgtT + (tap0 + 0) * 384 + c);
            const float4 w1 = *(const float4*)(wgtT + (tap0 + 1) * 384 + c);
            const float4 w2 = *(const float4*)(wgtT + (tap0 + 2) * 384 + c);
            const T* rowp = src + ((((size_t)b * 8 + dd) * 32 + hh) * 32) * 384 + c;
            #pragma unroll
            for (int p = 0; p < 10; ++p) {
                const int ww = w_base + p - 1;
                const float m = ((unsigned)ww < 32u) ? 1.f : 0.f;
                const int wwc = min(max(ww, 0), 31);
                float4 sv = ld4(rowp + (size_t)wwc * 384);
                sv.x *= m; sv.y *= m; sv.z *= m; sv.w *= m;
                if (p < 8) {
                    acc[p].x += sv.x * w0.x; acc[p].y += sv.y * w0.y;
                    acc[p].z += sv.z * w0.z; acc[p].w += sv.w * w0.w;
                }
                if (p >= 1 && p <= 8) {
                    acc[p-1].x += sv.x * w1.x; acc[p-1].y += sv.y * w1.y;
                    acc[p-1].z += sv.z * w1.z; acc[p-1].w += sv.w * w1.w;
                }
                if (p >= 2) {
                    acc[p-2].x += sv.x * w2.x; acc[p-2].y += sv.y * w2.y;
                    acc[p-2].z += sv.z * w2.z; acc[p-2].w += sv.w * w2.w;
                }
            }
        }
    }
    const size_t rowoff = ((((size_t)b * 8 + d) * 32 + h) * 32) * 384 + c;
    float4 r[8];
    __shared__ float2 part[32][96];
    #pragma unroll
    for (int o = 0; o < 8; ++o) {
        const size_t off = rowoff + (size_t)(w_base + o) * 384;
        const float4 s0 = ld4(src + off);
        r[o].x = s0.x + acc[o].x; r[o].y = s0.y + acc[o].y;
        r[o].z = s0.z + acc[o].z; r[o].w = s0.w + acc[o].w;
        ushort4 u;
        u.x = f2bf(r[o].x); u.y = f2bf(r[o].y); u.z = f2bf(r[o].z); u.w = f2bf(r[o].w);
        *(ushort4*)((unsigned short*)xf_out + off) = u;
        const float s = r[o].x + r[o].y + r[o].z + r[o].w;
        const float s2 = r[o].x*r[o].x + r[o].y*r[o].y + r[o].z*r[o].z + r[o].w*r[o].w;
        part[w_base + o][qd] = make_float2(s, s2);
    }
    __syncthreads();
    __shared__ float2 red[32][12];
    {
        const int tk = tid / 12, j = tid % 12;
        float s = 0.f, s2 = 0.f;
        #pragma unroll
        for (int u = 0; u < 8; ++u) {
            const float2 p = part[tk][j * 8 + u];
            s += p.x; s2 += p.y;
        }
        red[tk][j] = make_float2(s, s2);
    }
    __syncthreads();
    __shared__ float2 stats[32];
    if (tid < 32) {
        float s = 0.f, s2 = 0.f;
        #pragma unroll
        for (int j = 0; j < 12; ++j) { s += red[tid][j].x; s2 += red[tid][j].y; }
        const float mean = s * (1.f / 384.f);
        const float var = s2 * (1.f / 384.f) - mean * mean;
        stats[tid] = make_float2(mean, rsqrtf(var + 1e-5f));
    }
    __syncthreads();
    const float4 gv = *(const float4*)(gam + c);
    const float4 be = *(const float4*)(bet + c);
    #pragma unroll
    for (int o = 0; o < 8; ++o) {
        const int tk = w_base + o;
        const float2 st = stats[tk];
        ushort4 u;
        u.x = f2bf((r[o].x - st.x) * st.y * gv.x + be.x);
        u.y = f2bf((r[o].y - st.x) * st.y * gv.y + be.y);
        u.z = f2bf((r[o].z - st.x) * st.y * gv.z + be.z);
        u.w = f2bf((r[o].w - st.x) * st.y * gv.w + be.w);
        *(ushort4*)((unsigned short*)t_out + (size_t)(blk * 32 + tk) * 384 + c) = u;
    }
}

// ---------------------------------------------------------------------------
// GEMM: out[M,N] = A[M,K](bf16) @ BT[N,K]^T(bf16).  128x128 tile, BK=64,
// global_load_lds w16, XOR-swizzled LDS (conflict-free, verified R5).
// flags: 1 = gelu, 2 = out fp32 (else bf16), 4 = res bf16 (else fp32).
// ---------------------------------------------------------------------------
__global__ __launch_bounds__(256) void gemm128_kernel(
    const bf16* __restrict__ A, int lda,
    const bf16* __restrict__ BT, int ldb,
    void* outp, int ldo, const void* resp, const float* __restrict__ bias,
    int Nout, int K, int flags)
{
    __shared__ unsigned short As[128 * 64];
    __shared__ unsigned short Bs[128 * 64];
    const int tid = threadIdx.x;
    const int wid = tid >> 6, lane = tid & 63;
    const int m0 = blockIdx.y * 128, n0 = blockIdx.x * 128;
    const int moff = (wid >> 1) * 64, noff = (wid & 1) * 64;
    const int lrow = lane & 15, quad = lane >> 4;
    const int srow = lane >> 3;
    const int scol = ((lane & 7) ^ srow) * 8;
    const int sw = lrow & 7;

    f32x4 acc[4][4] = {};

    for (int k0 = 0; k0 < K; k0 += 64) {
        #pragma unroll
        for (int j = 0; j < 4; ++j) {
            const int r = (wid * 4 + j) * 8 + srow;
            GLD16(A + (size_t)(m0 + r) * lda + k0 + scol, As + (wid * 4 + j) * 512);
        }
        #pragma unroll
        for (int j = 0; j < 4; ++j) {
            const int r = (wid * 4 + j) * 8 + srow;
            GLD16(BT + (size_t)(n0 + r) * ldb + k0 + scol, Bs + (wid * 4 + j) * 512);
        }
        __syncthreads();
        #pragma unroll
        for (int ks = 0; ks < 64; ks += 32) {
            const int kc = (ks >> 3) + quad;
            const int koff = ((kc ^ sw) << 3);
            s16x8 af[4], bfr[4];
            #pragma unroll
            for (int i = 0; i < 4; ++i)
                af[i] = *(const s16x8*)(As + (moff + i * 16 + lrow) * 64 + koff);
            #pragma unroll
            for (int i = 0; i < 4; ++i)
                bfr[i] = *(const s16x8*)(Bs + (noff + i * 16 + lrow) * 64 + koff);
            #pragma unroll
            for (int mi = 0; mi < 4; ++mi)
                #pragma unroll
                for (int ni = 0; ni < 4; ++ni)
                    acc[mi][ni] = __builtin_amdgcn_mfma_f32_16x16x32_bf16(
                        af[mi], bfr[ni], acc[mi][ni], 0, 0, 0);
        }
        __syncthreads();
    }

    const bool gelu  = (flags & 1) != 0;
    const bool ofp32 = (flags & 2) != 0;
    const bool rbf16 = (flags & 4) != 0;
    const int rbase = quad * 4;
    #pragma unroll
    for (int mi = 0; mi < 4; ++mi) {
        #pragma unroll
        for (int ni = 0; ni < 4; ++ni) {
            const int gn = n0 + noff + ni * 16 + lrow;
            if (gn >= Nout) continue;
            const float bval = bias ? bias[gn] : 0.f;
            #pragma unroll
            for (int r = 0; r < 4; ++r) {
                const int gm = m0 + moff + mi * 16 + rbase + r;
                const size_t oi = (size_t)gm * ldo + gn;
                float v = acc[mi][ni][r] + bval;
                if (gelu) v = 0.5f * v * (1.f + erff(v * 0.70710678118f));
                if (resp) v += rbf16 ? bf2f(((const unsigned short*)resp)[oi])
                                     : ((const float*)resp)[oi];
                if (ofp32) ((float*)outp)[oi] = v;
                else       ((bf16*)outp)[oi] = __float2bfloat16(v);
            }
        }
    }
}

// ---------------------------------------------------------------------------
// Attention scores via MFMA: partial[c,d] = sum_{n in split} K[n,c]*V[n,d].
// grid (32 bgh, 32 splits), block 64 (1 wave).
// ---------------------------------------------------------------------------
__global__ __launch_bounds__(64) void attp_kernel(
    const bf16* __restrict__ kvb, float* __restrict__ attp)
{
    const int bgh = blockIdx.x, split = blockIdx.y;
    const int b = bgh >> 3, rr = bgh & 7, g = rr >> 2, h = rr & 3;
    const int kcol = g * 192 + h * 48, vcol = 384 + g * 192 + h * 48;
    __shared__ unsigned short Ks[256 * 48];
    __shared__ unsigned short Vs[256 * 48];
    const int lane = threadIdx.x;

    const size_t rowbase = (size_t)(b * 8192 + split * 256) * 768;
    for (int i = lane; i < 256 * 6; i += 64) {
        const int row = i / 6, part = i % 6;
        const size_t gi = rowbase + (size_t)row * 768;
        *(uint4*)(Ks + row * 48 + part * 8) = *(const uint4*)(kvb + gi + kcol + part * 8);
        *(uint4*)(Vs + row * 48 + part * 8) = *(const uint4*)(kvb + gi + vcol + part * 8);
    }
    __syncthreads();

    f32x4 acc[3][3] = {};
    const int col = lane & 15, kb = (lane >> 4) * 8;
    for (int ks = 0; ks < 256; ks += 32) {
        s16x8 af[3], bfr[3];
        #pragma unroll
        for (int t3 = 0; t3 < 3; ++t3) {
            #pragma unroll
            for (int j = 0; j < 8; ++j) {
                const int tok = ks + kb + j;
                af[t3][j]  = (short)Ks[tok * 48 + t3 * 16 + col];
                bfr[t3][j] = (short)Vs[tok * 48 + t3 * 16 + col];
            }
        }
        #pragma unroll
        for (int ct = 0; ct < 3; ++ct)
            #pragma unroll
            for (int dt = 0; dt < 3; ++dt)
                acc[ct][dt] = __builtin_amdgcn_mfma_f32_16x16x32_bf16(
                    af[ct], bfr[dt], acc[ct][dt], 0, 0, 0);
    }
    const float scale = 0.14433756729740643f;  // 48^-0.5
    float* op = attp + ((size_t)bgh * 32 + split) * 2304;
    const int rbase = (lane >> 4) * 4;
    #pragma unroll
    for (int ct = 0; ct < 3; ++ct)
        #pragma unroll
        for (int dt = 0; dt < 3; ++dt)
            #pragma unroll
            for (int r = 0; r < 4; ++r)
                op[(ct * 16 + rbase + r) * 48 + dt * 16 + col] = scale * acc[ct][dt][r];
}

// ---------------------------------------------------------------------------
// reduce 32 splits, fp32 softmax over rows, cast to bf16. grid 32, block 256.
// ---------------------------------------------------------------------------
__global__ __launch_bounds__(256) void attred_kernel(
    const float* __restrict__ attp, bf16* __restrict__ att)
{
    const int bgh = blockIdx.x, tid = threadIdx.x;
    __shared__ float s[2304];
    for (int i = tid; i < 2304; i += 256) {
        float a = 0.f;
        for (int sp = 0; sp < 32; ++sp) a += attp[((size_t)bgh * 32 + sp) * 2304 + i];
        s[i] = a;
    }
    __syncthreads();
    if (tid < 48) {
        const int base = tid * 48;
        float mx = -1e30f;
        for (int d = 0; d < 48; ++d) mx = fmaxf(mx, s[base + d]);
        float sum = 0.f;
        for (int d = 0; d < 48; ++d) sum += expf(s[base + d] - mx);
        float inv = 1.f / sum;
        for (int d = 0; d < 48; ++d)
            att[(size_t)bgh * 2304 + base + d] = __float2bfloat16(expf(s[base + d] - mx) * inv);
    }
}

// ---------------------------------------------------------------------------
// y = Q_g(8192x48) @ att^T(48x48) per (b,h2g), MFMA, K=48 padded to 64.
// Scrambled write: row' = b*8192 + h2g*1024 + n/8, col' = (n%8)*48 + d.
// ---------------------------------------------------------------------------
__global__ __launch_bounds__(256) void y_kernel(
    const bf16* __restrict__ q, const bf16* __restrict__ att, bf16* __restrict__ y)
{
    const int m0 = blockIdx.x * 128;
    const int b = blockIdx.y >> 3, h2g = blockIdx.y & 7;
    const int g = h2g & 1, hh = h2g >> 1;
    const int bgh = b * 8 + g * 4 + hh;
    const int tid = threadIdx.x, wid = tid >> 6, lane = tid & 63;
    __shared__ unsigned short Qs[128 * 64];
    __shared__ unsigned short Ats[48 * 64];

    for (int i = tid; i < 128 * 6; i += 256) {
        const int row = i / 6, part = i % 6;
        *(uint4*)(Qs + row * 64 + part * 8) =
            *(const uint4*)(q + (size_t)(b * 8192 + m0 + row) * 96 + g * 48 + part * 8);
    }
    {
        const int row = tid / 2, half = tid & 1;
        *(uint4*)(Qs + row * 64 + 48 + half * 8) = make_uint4(0, 0, 0, 0);
    }
    for (int i = tid; i < 48 * 6; i += 256) {
        const int row = i / 6, part = i % 6;
        *(uint4*)(Ats + row * 64 + part * 8) =
            *(const uint4*)(att + (size_t)bgh * 2304 + row * 48 + part * 8);
    }
    for (int i = tid; i < 96; i += 256) {
        const int row = i / 2, half = i & 1;
        *(uint4*)(Ats + row * 64 + 48 + half * 8) = make_uint4(0, 0, 0, 0);
    }
    __syncthreads();

    const int moff = wid * 32;
    const int col = lane & 15, kb = (lane >> 4) * 8;
    f32x4 acc[2][3] = {};
    #pragma unroll
    for (int ks = 0; ks < 64; ks += 32) {
        s16x8 af[2], bfr[3];
        #pragma unroll
        for (int mt = 0; mt < 2; ++mt)
            af[mt] = *(const s16x8*)(Qs + (moff + mt * 16 + col) * 64 + ks + kb);
        #pragma unroll
        for (int nt = 0; nt < 3; ++nt)
            bfr[nt] = *(const s16x8*)(Ats + (nt * 16 + col) * 64 + ks + kb);
        #pragma unroll
        for (int mt = 0; mt < 2; ++mt)
            #pragma unroll
            for (int nt = 0; nt < 3; ++nt)
                acc[mt][nt] = __builtin_amdgcn_mfma_f32_16x16x32_bf16(
                    af[mt], bfr[nt], acc[mt][nt], 0, 0, 0);
    }
    const int rbase = (lane >> 4) * 4;
    #pragma unroll
    for (int mt = 0; mt < 2; ++mt) {
        #pragma unroll
        for (int nt = 0; nt < 3; ++nt) {
            const int d = nt * 16 + col;
            #pragma unroll
            for (int r = 0; r < 4; ++r) {
                const int n = m0 + moff + mt * 16 + rbase + r;
                y[((size_t)b * 8192 + h2g * 1024 + (n >> 3)) * 384 + (n & 7) * 48 + d] =
                    __float2bfloat16(acc[mt][nt][r]);
            }
        }
    }
}

// ---------------------------------------------------------------------------
extern "C" void kernel_launch(void* const* d_in, const int* in_sizes, int n_in,
                              void* d_out, int out_size, void* d_ws, size_t ws_size,
                              hipStream_t stream)
{
    (void)in_sizes; (void)n_in; (void)out_size; (void)ws_size;
    const float* x      = (const float*)d_in[0];
    const float* cpe0_w = (const float*)d_in[2];
    const float* cpe0_b = (const float*)d_in[3];
    const float* cpe1_w = (const float*)d_in[4];
    const float* cpe1_b = (const float*)d_in[5];
    const float* n1g    = (const float*)d_in[6];
    const float* n1b    = (const float*)d_in[7];
    const float* q_w    = (const float*)d_in[8];
    const float* kv_w   = (const float*)d_in[9];
    const float* proj_w = (const float*)d_in[10];
    const float* proj_b = (const float*)d_in[11];
    const float* n2g    = (const float*)d_in[12];
    const float* n2b    = (const float*)d_in[13];
    const float* w1     = (const float*)d_in[14];
    const float* b1     = (const float*)d_in[15];
    const float* w2     = (const float*)d_in[16];
    const float* b2     = (const float*)d_in[17];

    char* ws = (char*)d_ws;
    // persistent weights: 0 .. 3.3 MiB
    bf16*  qwT  = (bf16*)(ws + 0);
    bf16*  kvwT = (bf16*)(ws + 98304);
    bf16*  pwT  = (bf16*)(ws + 688128);
    bf16*  w1T  = (bf16*)(ws + 983040);
    bf16*  w2T  = (bf16*)(ws + 2162688);
    float* wt0  = (float*)(ws + 3342336);
    float* wt1  = (float*)(ws + 3383808);
    // scratch zone A (4..100 MiB): phase-1 buffers, then h1 (96 MiB)
    bf16*  xf   = (bf16*)(ws + 4194304);     // 24 MiB residual1 bf16
    bf16*  qb   = (bf16*)(ws + 29360128);    //  6 MiB
    float* attp = (float*)(ws + 35651584);   //  9 MiB
    bf16*  att  = (bf16*)(ws + 45088768);    //  144 KiB
    bf16*  yb   = (bf16*)(ws + 46137344);    // 24 MiB
    bf16*  h1   = (bf16*)(ws + 4194304);     // 96 MiB [32768][1536] (phase-2)
    // fixed tail
    bf16*  t    = (bf16*)(ws + 104857600);   // 24 MiB LN out
    bf16*  kv   = (bf16*)(ws + 130023424);   // 48 MiB [32768][768]
    bf16*  xf3  = (bf16*)(ws + 130023424);   // 24 MiB (aliases kv; kv dead first)

    // 0. merged prep
    prep_kernel<<<dim3(6609), dim3(256), 0, stream>>>(
        q_w, kv_w, proj_w, w1, w2, cpe0_w, cpe1_w,
        qwT, kvwT, pwT, w1T, w2T, wt0, wt1);

    // 1. CPE0 + LN1: xf(bf16) = x + dwconv(x) + b ; t = LN(xf)
    cpe_ln_kernel<float><<<dim3(1024), dim3(384), 0, stream>>>(
        x, wt0, cpe0_b, n1g, n1b, xf, t);
    // 2/3. q and kv projections
    gemm128_kernel<<<dim3(1, 256), dim3(256), 0, stream>>>(
        t, 384, qwT, 384, qb, 96, nullptr, nullptr, 96, 384, 0);
    gemm128_kernel<<<dim3(6, 256), dim3(256), 0, stream>>>(
        t, 384, kvwT, 384, kv, 768, nullptr, nullptr, 768, 384, 0);
    // 4/5. channel-attention scores + softmax
    attp_kernel<<<dim3(32, 32), dim3(64), 0, stream>>>(kv, attp);
    attred_kernel<<<dim3(32), dim3(256), 0, stream>>>(attp, att);
    // 6. y = q @ att^T with scrambled reshape
    y_kernel<<<dim3(64, 32), dim3(256), 0, stream>>>(qb, att, yb);
    // 7. proj (in-place bf16 residual): xf = yb @ pw + pb + xf
    gemm128_kernel<<<dim3(3, 256), dim3(256), 0, stream>>>(
        yb, 384, pwT, 384, xf, 384, xf, proj_b, 384, 384, 4);
    // 8. CPE1 + LN2: xf3(bf16) = xf + dwconv(xf) + b ; t = LN(xf3)
    cpe_ln_kernel<bf16><<<dim3(1024), dim3(384), 0, stream>>>(
        xf, wt1, cpe1_b, n2g, n2b, xf3, t);
    // 9. MLP full-M: h1 = gelu(t@W1+b1); out = h1@W2 + b2 + xf3 (fp32)
    gemm128_kernel<<<dim3(12, 256), dim3(256), 0, stream>>>(
        t, 384, w1T, 384, h1, 1536, nullptr, b1, 1536, 384, 1);
    gemm128_kernel<<<dim3(3, 256), dim3(256), 0, stream>>>(
        h1, 1536, w2T, 1536, d_out, 384, xf3, b2, 384, 1536, 2 | 4);
}

// Round 7
// 526.244 us; speedup vs baseline: 4.0447x; 1.0416x over previous
//
#include <hip/hip_runtime.h>
#include <hip/hip_bf16.h>
#include <math.h>

using bf16 = __hip_bfloat16;
typedef __attribute__((ext_vector_type(8))) short s16x8;
typedef __attribute__((ext_vector_type(4))) float f32x4;

__device__ __forceinline__ float bf2f(unsigned short u) {
    return __uint_as_float(((unsigned int)u) << 16);
}
__device__ __forceinline__ unsigned short f2bf(float f) {
    union { bf16 b; unsigned short u; } cv; cv.b = __float2bfloat16(f); return cv.u;
}
__device__ __forceinline__ float4 ld4(const float* p) { return *(const float4*)p; }
__device__ __forceinline__ float4 ld4(const bf16* p) {
    ushort4 u = *(const ushort4*)p;
    return make_float4(bf2f(u.x), bf2f(u.y), bf2f(u.z), bf2f(u.w));
}

// fast exact-grade gelu: A&S 7.1.26 erf, |eps| <= 1.5e-7, branch-free
__device__ __forceinline__ float gelu_f(float v) {
    const float x = 0.70710678118f * v;
    const float ax = fabsf(x);
    const float t = __builtin_amdgcn_rcpf(fmaf(0.3275911f, ax, 1.f));
    float p = fmaf(1.061405429f, t, -1.453152027f);
    p = fmaf(p, t, 1.421413741f);
    p = fmaf(p, t, -0.284496736f);
    p = fmaf(p, t, 0.254829592f);
    p *= t;
    const float e = __expf(-x * x);
    const float er = copysignf(fmaf(-p, e, 1.f), x);
    return 0.5f * v * (1.f + er);
}

#define GLD16(g, l) __builtin_amdgcn_global_load_lds( \
    (const __attribute__((address_space(1))) unsigned int*)(const void*)(g), \
    (__attribute__((address_space(3))) unsigned int*)(void*)(l), 16, 0, 0)

// ---------------------------------------------------------------------------
// merged prep (index-range segmented).
// qkvT[896][384]: rows 0..95 = q_w^T, 96..127 = 0, 128..895 = kv_w^T.
// ---------------------------------------------------------------------------
__device__ __forceinline__ void wtbT(const float* __restrict__ src,
                                     bf16* __restrict__ dst, int K, int N, int i)
{
    int n = i / K, k = i % K;
    dst[i] = (n < N) ? __float2bfloat16(src[k * N + n]) : __float2bfloat16(0.f);
}

__global__ __launch_bounds__(256) void prep_kernel(
    const float* q_w, const float* kv_w, const float* proj_w,
    const float* w1, const float* w2,
    const float* cpe0_w, const float* cpe1_w,
    bf16* qkvT, bf16* pwT, bf16* w1T, bf16* w2T,
    float* wt0, float* wt1)
{
    int i = blockIdx.x * 256 + threadIdx.x;
    if (i < 344064) {                                   // [896][384]
        int n = i / 384, k = i % 384;
        float v = 0.f;
        if (n < 96)       v = q_w[k * 96 + n];
        else if (n >= 128) v = kv_w[k * 768 + (n - 128)];
        qkvT[i] = __float2bfloat16(v);
    }
    else if (i < 491520)  wtbT(proj_w, pwT,  384, 384,  i - 344064);
    else if (i < 1081344) wtbT(w1,     w1T,  384, 1536, i - 491520);
    else if (i < 1671168) wtbT(w2,     w2T,  1536, 384, i - 1081344);
    else if (i < 1681536) { int j = i - 1671168; wt0[(j % 27) * 384 + j / 27] = cpe0_w[j]; }
    else if (i < 1691904) { int j = i - 1681536; wt1[(j % 27) * 384 + j / 27] = cpe1_w[j]; }
}

// ---------------------------------------------------------------------------
// Depthwise 3x3x3 conv + bias + residual + FUSED LayerNorm.
// Block = one (b,d,h) row: 32 tokens x 384 ch. src fp32 or bf16 (templated);
// xf_out bf16 (pre-LN residual), t_out bf16 (LN result).
// ---------------------------------------------------------------------------
template <typename T>
__global__ __launch_bounds__(384) void cpe_ln_kernel(
    const T* __restrict__ src, const float* __restrict__ wgtT,
    const float* __restrict__ bias, const float* __restrict__ gam,
    const float* __restrict__ bet, bf16* __restrict__ xf_out,
    bf16* __restrict__ t_out)
{
    const int tid = threadIdx.x;
    const int qd = tid % 96, c = qd * 4;
    const int wseg = tid / 96, w_base = wseg * 8;
    const int blk = blockIdx.x;
    const int h = blk & 31, d = (blk >> 5) & 7, b = blk >> 8;

    const float4 bv = *(const float4*)(bias + c);
    float4 acc[8];
    #pragma unroll
    for (int o = 0; o < 8; ++o) acc[o] = bv;

    #pragma unroll
    for (int kd = 0; kd < 3; ++kd) {
        const int dd = d + kd - 1;
        if ((unsigned)dd >= 8u) continue;
        #pragma unroll
        for (int kh = 0; kh < 3; ++kh) {
            const int hh = h + kh - 1;
            if ((unsigned)hh >= 32u) continue;
            const int tap0 = kd * 9 + kh * 3;
            const float4 w0 = *(const float4*)(wgtT + (tap0 + 0) * 384 + c);
            const float4 w1 = *(const float4*)(wgtT + (tap0 + 1) * 384 + c);
            const float4 w2 = *(const float4*)(wgtT + (tap0 + 2) * 384 + c);
            const T* rowp = src + ((((size_t)b * 8 + dd) * 32 + hh) * 32) * 384 + c;
            #pragma unroll
            for (int p = 0; p < 10; ++p) {
                const int ww = w_base + p - 1;
                const float m = ((unsigned)ww < 32u) ? 1.f : 0.f;
                const int wwc = min(max(ww, 0), 31);
                float4 sv = ld4(rowp + (size_t)wwc * 384);
                sv.x *= m; sv.y *= m; sv.z *= m; sv.w *= m;
                if (p < 8) {
                    acc[p].x += sv.x * w0.x; acc[p].y += sv.y * w0.y;
                    acc[p].z += sv.z * w0.z; acc[p].w += sv.w * w0.w;
                }
                if (p >= 1 && p <= 8) {
                    acc[p-1].x += sv.x * w1.x; acc[p-1].y += sv.y * w1.y;
                    acc[p-1].z += sv.z * w1.z; acc[p-1].w += sv.w * w1.w;
                }
                if (p >= 2) {
                    acc[p-2].x += sv.x * w2.x; acc[p-2].y += sv.y * w2.y;
                    acc[p-2].z += sv.z * w2.z; acc[p-2].w += sv.w * w2.w;
                }
            }
        }
    }
    const size_t rowoff = ((((size_t)b * 8 + d) * 32 + h) * 32) * 384 + c;
    float4 r[8];
    __shared__ float2 part[32][96];
    #pragma unroll
    for (int o = 0; o < 8; ++o) {
        const size_t off = rowoff + (size_t)(w_base + o) * 384;
        const float4 s0 = ld4(src + off);
        r[o].x = s0.x + acc[o].x; r[o].y = s0.y + acc[o].y;
        r[o].z = s0.z + acc[o].z; r[o].w = s0.w + acc[o].w;
        ushort4 u;
        u.x = f2bf(r[o].x); u.y = f2bf(r[o].y); u.z = f2bf(r[o].z); u.w = f2bf(r[o].w);
        *(ushort4*)((unsigned short*)xf_out + off) = u;
        const float s = r[o].x + r[o].y + r[o].z + r[o].w;
        const float s2 = r[o].x*r[o].x + r[o].y*r[o].y + r[o].z*r[o].z + r[o].w*r[o].w;
        part[w_base + o][qd] = make_float2(s, s2);
    }
    __syncthreads();
    __shared__ float2 red[32][12];
    {
        const int tk = tid / 12, j = tid % 12;
        float s = 0.f, s2 = 0.f;
        #pragma unroll
        for (int u = 0; u < 8; ++u) {
            const float2 p = part[tk][j * 8 + u];
            s += p.x; s2 += p.y;
        }
        red[tk][j] = make_float2(s, s2);
    }
    __syncthreads();
    __shared__ float2 stats[32];
    if (tid < 32) {
        float s = 0.f, s2 = 0.f;
        #pragma unroll
        for (int j = 0; j < 12; ++j) { s += red[tid][j].x; s2 += red[tid][j].y; }
        const float mean = s * (1.f / 384.f);
        const float var = s2 * (1.f / 384.f) - mean * mean;
        stats[tid] = make_float2(mean, rsqrtf(var + 1e-5f));
    }
    __syncthreads();
    const float4 gv = *(const float4*)(gam + c);
    const float4 be = *(const float4*)(bet + c);
    #pragma unroll
    for (int o = 0; o < 8; ++o) {
        const int tk = w_base + o;
        const float2 st = stats[tk];
        ushort4 u;
        u.x = f2bf((r[o].x - st.x) * st.y * gv.x + be.x);
        u.y = f2bf((r[o].y - st.x) * st.y * gv.y + be.y);
        u.z = f2bf((r[o].z - st.x) * st.y * gv.z + be.z);
        u.w = f2bf((r[o].w - st.x) * st.y * gv.w + be.w);
        *(ushort4*)((unsigned short*)t_out + (size_t)(blk * 32 + tk) * 384 + c) = u;
    }
}

// ---------------------------------------------------------------------------
// GEMM: out[M,N] = A[M,K](bf16) @ BT[N,K]^T(bf16).  128x128 tile, BK=64,
// global_load_lds w16, XOR-swizzled LDS (conflict-free).
// GRID = (Mtiles, Ntiles): m on x so n-siblings sharing an A-tile are 256
// apart in dispatch order -> same XCD -> A served from one L2.
// flags: 1 = gelu, 2 = out fp32 (else bf16), 4 = res bf16 (else fp32).
// ---------------------------------------------------------------------------
__global__ __launch_bounds__(256) void gemm128_kernel(
    const bf16* __restrict__ A, int lda,
    const bf16* __restrict__ BT, int ldb,
    void* outp, int ldo, const void* resp, const float* __restrict__ bias,
    int Nout, int K, int flags)
{
    __shared__ unsigned short As[128 * 64];
    __shared__ unsigned short Bs[128 * 64];
    const int tid = threadIdx.x;
    const int wid = tid >> 6, lane = tid & 63;
    const int m0 = blockIdx.x * 128, n0 = blockIdx.y * 128;
    const int moff = (wid >> 1) * 64, noff = (wid & 1) * 64;
    const int lrow = lane & 15, quad = lane >> 4;
    const int srow = lane >> 3;
    const int scol = ((lane & 7) ^ srow) * 8;
    const int sw = lrow & 7;

    f32x4 acc[4][4] = {};

    for (int k0 = 0; k0 < K; k0 += 64) {
        #pragma unroll
        for (int j = 0; j < 4; ++j) {
            const int r = (wid * 4 + j) * 8 + srow;
            GLD16(A + (size_t)(m0 + r) * lda + k0 + scol, As + (wid * 4 + j) * 512);
        }
        #pragma unroll
        for (int j = 0; j < 4; ++j) {
            const int r = (wid * 4 + j) * 8 + srow;
            GLD16(BT + (size_t)(n0 + r) * ldb + k0 + scol, Bs + (wid * 4 + j) * 512);
        }
        __syncthreads();
        #pragma unroll
        for (int ks = 0; ks < 64; ks += 32) {
            const int kc = (ks >> 3) + quad;
            const int koff = ((kc ^ sw) << 3);
            s16x8 af[4], bfr[4];
            #pragma unroll
            for (int i = 0; i < 4; ++i)
                af[i] = *(const s16x8*)(As + (moff + i * 16 + lrow) * 64 + koff);
            #pragma unroll
            for (int i = 0; i < 4; ++i)
                bfr[i] = *(const s16x8*)(Bs + (noff + i * 16 + lrow) * 64 + koff);
            #pragma unroll
            for (int mi = 0; mi < 4; ++mi)
                #pragma unroll
                for (int ni = 0; ni < 4; ++ni)
                    acc[mi][ni] = __builtin_amdgcn_mfma_f32_16x16x32_bf16(
                        af[mi], bfr[ni], acc[mi][ni], 0, 0, 0);
        }
        __syncthreads();
    }

    const bool gelu  = (flags & 1) != 0;
    const bool ofp32 = (flags & 2) != 0;
    const bool rbf16 = (flags & 4) != 0;
    const int rbase = quad * 4;
    #pragma unroll
    for (int mi = 0; mi < 4; ++mi) {
        #pragma unroll
        for (int ni = 0; ni < 4; ++ni) {
            const int gn = n0 + noff + ni * 16 + lrow;
            if (gn >= Nout) continue;
            const float bval = bias ? bias[gn] : 0.f;
            #pragma unroll
            for (int r = 0; r < 4; ++r) {
                const int gm = m0 + moff + mi * 16 + rbase + r;
                const size_t oi = (size_t)gm * ldo + gn;
                float v = acc[mi][ni][r] + bval;
                if (gelu) v = gelu_f(v);
                if (resp) v += rbf16 ? bf2f(((const unsigned short*)resp)[oi])
                                     : ((const float*)resp)[oi];
                if (ofp32) ((float*)outp)[oi] = v;
                else       ((bf16*)outp)[oi] = __float2bfloat16(v);
            }
        }
    }
}

// ---------------------------------------------------------------------------
// Attention scores via MFMA: partial[c,d] = sum_{n in split} K[n,c]*V[n,d].
// qkv layout: row token, 896 cols: k at 128+g*192+h*48, v at 512+g*192+h*48.
// grid (32 bgh, 32 splits), block 64 (1 wave).
// ---------------------------------------------------------------------------
__global__ __launch_bounds__(64) void attp_kernel(
    const bf16* __restrict__ qkv, float* __restrict__ attp)
{
    const int bgh = blockIdx.x, split = blockIdx.y;
    const int b = bgh >> 3, rr = bgh & 7, g = rr >> 2, h = rr & 3;
    const int kcol = 128 + g * 192 + h * 48, vcol = 512 + g * 192 + h * 48;
    __shared__ unsigned short Ks[256 * 48];
    __shared__ unsigned short Vs[256 * 48];
    const int lane = threadIdx.x;

    const size_t rowbase = (size_t)(b * 8192 + split * 256) * 896;
    for (int i = lane; i < 256 * 6; i += 64) {
        const int row = i / 6, part = i % 6;
        const size_t gi = rowbase + (size_t)row * 896;
        *(uint4*)(Ks + row * 48 + part * 8) = *(const uint4*)(qkv + gi + kcol + part * 8);
        *(uint4*)(Vs + row * 48 + part * 8) = *(const uint4*)(qkv + gi + vcol + part * 8);
    }
    __syncthreads();

    f32x4 acc[3][3] = {};
    const int col = lane & 15, kb = (lane >> 4) * 8;
    for (int ks = 0; ks < 256; ks += 32) {
        s16x8 af[3], bfr[3];
        #pragma unroll
        for (int t3 = 0; t3 < 3; ++t3) {
            #pragma unroll
            for (int j = 0; j < 8; ++j) {
                const int tok = ks + kb + j;
                af[t3][j]  = (short)Ks[tok * 48 + t3 * 16 + col];
                bfr[t3][j] = (short)Vs[tok * 48 + t3 * 16 + col];
            }
        }
        #pragma unroll
        for (int ct = 0; ct < 3; ++ct)
            #pragma unroll
            for (int dt = 0; dt < 3; ++dt)
                acc[ct][dt] = __builtin_amdgcn_mfma_f32_16x16x32_bf16(
                    af[ct], bfr[dt], acc[ct][dt], 0, 0, 0);
    }
    const float scale = 0.14433756729740643f;  // 48^-0.5
    float* op = attp + ((size_t)bgh * 32 + split) * 2304;
    const int rbase = (lane >> 4) * 4;
    #pragma unroll
    for (int ct = 0; ct < 3; ++ct)
        #pragma unroll
        for (int dt = 0; dt < 3; ++dt)
            #pragma unroll
            for (int r = 0; r < 4; ++r)
                op[(ct * 16 + rbase + r) * 48 + dt * 16 + col] = scale * acc[ct][dt][r];
}

// ---------------------------------------------------------------------------
// reduce 32 splits, fp32 softmax over rows, cast to bf16. grid 32, block 256.
// ---------------------------------------------------------------------------
__global__ __launch_bounds__(256) void attred_kernel(
    const float* __restrict__ attp, bf16* __restrict__ att)
{
    const int bgh = blockIdx.x, tid = threadIdx.x;
    __shared__ float s[2304];
    for (int i = tid; i < 2304; i += 256) {
        float a = 0.f;
        for (int sp = 0; sp < 32; ++sp) a += attp[((size_t)bgh * 32 + sp) * 2304 + i];
        s[i] = a;
    }
    __syncthreads();
    if (tid < 48) {
        const int base = tid * 48;
        float mx = -1e30f;
        for (int d = 0; d < 48; ++d) mx = fmaxf(mx, s[base + d]);
        float sum = 0.f;
        for (int d = 0; d < 48; ++d) sum += expf(s[base + d] - mx);
        float inv = 1.f / sum;
        for (int d = 0; d < 48; ++d)
            att[(size_t)bgh * 2304 + base + d] = __float2bfloat16(expf(s[base + d] - mx) * inv);
    }
}

// ---------------------------------------------------------------------------
// y = Q_g(8192x48) @ att^T(48x48) per (b,h2g), MFMA, K=48 padded to 64.
// Q read from merged qkv (ld 896, cols g*48..). Scrambled write.
// ---------------------------------------------------------------------------
__global__ __launch_bounds__(256) void y_kernel(
    const bf16* __restrict__ qkv, const bf16* __restrict__ att, bf16* __restrict__ y)
{
    const int m0 = blockIdx.x * 128;
    const int b = blockIdx.y >> 3, h2g = blockIdx.y & 7;
    const int g = h2g & 1, hh = h2g >> 1;
    const int bgh = b * 8 + g * 4 + hh;
    const int tid = threadIdx.x, wid = tid >> 6, lane = tid & 63;
    __shared__ unsigned short Qs[128 * 64];
    __shared__ unsigned short Ats[48 * 64];

    for (int i = tid; i < 128 * 6; i += 256) {
        const int row = i / 6, part = i % 6;
        *(uint4*)(Qs + row * 64 + part * 8) =
            *(const uint4*)(qkv + (size_t)(b * 8192 + m0 + row) * 896 + g * 48 + part * 8);
    }
    {
        const int row = tid / 2, half = tid & 1;
        *(uint4*)(Qs + row * 64 + 48 + half * 8) = make_uint4(0, 0, 0, 0);
    }
    for (int i = tid; i < 48 * 6; i += 256) {
        const int row = i / 6, part = i % 6;
        *(uint4*)(Ats + row * 64 + part * 8) =
            *(const uint4*)(att + (size_t)bgh * 2304 + row * 48 + part * 8);
    }
    for (int i = tid; i < 96; i += 256) {
        const int row = i / 2, half = i & 1;
        *(uint4*)(Ats + row * 64 + 48 + half * 8) = make_uint4(0, 0, 0, 0);
    }
    __syncthreads();

    const int moff = wid * 32;
    const int col = lane & 15, kb = (lane >> 4) * 8;
    f32x4 acc[2][3] = {};
    #pragma unroll
    for (int ks = 0; ks < 64; ks += 32) {
        s16x8 af[2], bfr[3];
        #pragma unroll
        for (int mt = 0; mt < 2; ++mt)
            af[mt] = *(const s16x8*)(Qs + (moff + mt * 16 + col) * 64 + ks + kb);
        #pragma unroll
        for (int nt = 0; nt < 3; ++nt)
            bfr[nt] = *(const s16x8*)(Ats + (nt * 16 + col) * 64 + ks + kb);
        #pragma unroll
        for (int mt = 0; mt < 2; ++mt)
            #pragma unroll
            for (int nt = 0; nt < 3; ++nt)
                acc[mt][nt] = __builtin_amdgcn_mfma_f32_16x16x32_bf16(
                    af[mt], bfr[nt], acc[mt][nt], 0, 0, 0);
    }
    const int rbase = (lane >> 4) * 4;
    #pragma unroll
    for (int mt = 0; mt < 2; ++mt) {
        #pragma unroll
        for (int nt = 0; nt < 3; ++nt) {
            const int d = nt * 16 + col;
            #pragma unroll
            for (int r = 0; r < 4; ++r) {
                const int n = m0 + moff + mt * 16 + rbase + r;
                y[((size_t)b * 8192 + h2g * 1024 + (n >> 3)) * 384 + (n & 7) * 48 + d] =
                    __float2bfloat16(acc[mt][nt][r]);
            }
        }
    }
}

// ---------------------------------------------------------------------------
extern "C" void kernel_launch(void* const* d_in, const int* in_sizes, int n_in,
                              void* d_out, int out_size, void* d_ws, size_t ws_size,
                              hipStream_t stream)
{
    (void)in_sizes; (void)n_in; (void)out_size; (void)ws_size;
    const float* x      = (const float*)d_in[0];
    const float* cpe0_w = (const float*)d_in[2];
    const float* cpe0_b = (const float*)d_in[3];
    const float* cpe1_w = (const float*)d_in[4];
    const float* cpe1_b = (const float*)d_in[5];
    const float* n1g    = (const float*)d_in[6];
    const float* n1b    = (const float*)d_in[7];
    const float* q_w    = (const float*)d_in[8];
    const float* kv_w   = (const float*)d_in[9];
    const float* proj_w = (const float*)d_in[10];
    const float* proj_b = (const float*)d_in[11];
    const float* n2g    = (const float*)d_in[12];
    const float* n2b    = (const float*)d_in[13];
    const float* w1     = (const float*)d_in[14];
    const float* b1     = (const float*)d_in[15];
    const float* w2     = (const float*)d_in[16];
    const float* b2     = (const float*)d_in[17];

    char* ws = (char*)d_ws;
    // persistent weights: 0 .. 3.3 MiB
    bf16*  qkvT = (bf16*)(ws + 0);           // [896][384]
    bf16*  pwT  = (bf16*)(ws + 688128);      // [384][384]
    bf16*  w1T  = (bf16*)(ws + 983040);      // [1536][384]
    bf16*  w2T  = (bf16*)(ws + 2162688);     // [384][1536]
    float* wt0  = (float*)(ws + 3342336);
    float* wt1  = (float*)(ws + 3383808);
    // dynamic buffers
    bf16*  xf   = (bf16*)(ws + 4194304);     // 24 MiB residual1
    bf16*  qkv  = (bf16*)(ws + 29360128);    // 56 MiB [32768][896]
    float* attp = (float*)(ws + 88080384);   //  9 MiB
    bf16*  att  = (bf16*)(ws + 97517568);    //  144 KiB
    bf16*  yb   = (bf16*)(ws + 98566144);    // 24 MiB
    bf16*  t    = (bf16*)(ws + 123731968);   // 24 MiB LN out
    bf16*  xf3  = (bf16*)(ws + 148897792);   // 24 MiB residual2
    bf16*  h1   = (bf16*)(ws + 4194304);     // 96 MiB (phase-2; aliases xf..yb, all dead)

    // 0. merged prep
    prep_kernel<<<dim3(6609), dim3(256), 0, stream>>>(
        q_w, kv_w, proj_w, w1, w2, cpe0_w, cpe1_w,
        qkvT, pwT, w1T, w2T, wt0, wt1);

    // 1. CPE0 + LN1: xf(bf16) = x + dwconv(x) + b ; t = LN(xf)
    cpe_ln_kernel<float><<<dim3(1024), dim3(384), 0, stream>>>(
        x, wt0, cpe0_b, n1g, n1b, xf, t);
    // 2. merged q+kv projection: qkv = t @ qkvT^T   (grid m-major for XCD locality)
    gemm128_kernel<<<dim3(256, 7), dim3(256), 0, stream>>>(
        t, 384, qkvT, 384, qkv, 896, nullptr, nullptr, 896, 384, 0);
    // 3/4. channel-attention scores + softmax
    attp_kernel<<<dim3(32, 32), dim3(64), 0, stream>>>(qkv, attp);
    attred_kernel<<<dim3(32), dim3(256), 0, stream>>>(attp, att);
    // 5. y = q @ att^T with scrambled reshape
    y_kernel<<<dim3(64, 32), dim3(256), 0, stream>>>(qkv, att, yb);
    // 6. proj (in-place bf16 residual): xf = yb @ pw + pb + xf
    gemm128_kernel<<<dim3(256, 3), dim3(256), 0, stream>>>(
        yb, 384, pwT, 384, xf, 384, xf, proj_b, 384, 384, 4);
    // 7. CPE1 + LN2: xf3(bf16) = xf + dwconv(xf) + b ; t = LN(xf3)
    cpe_ln_kernel<bf16><<<dim3(1024), dim3(384), 0, stream>>>(
        xf, wt1, cpe1_b, n2g, n2b, xf3, t);
    // 8. MLP: h1 = gelu(t@W1+b1); out = h1@W2 + b2 + xf3 (fp32)
    gemm128_kernel<<<dim3(256, 12), dim3(256), 0, stream>>>(
        t, 384, w1T, 384, h1, 1536, nullptr, b1, 1536, 384, 1);
    gemm128_kernel<<<dim3(256, 3), dim3(256), 0, stream>>>(
        h1, 1536, w2T, 1536, d_out, 384, xf3, b2, 384, 1536, 2 | 4);
}